// Round 9
// baseline (668.963 us; speedup 1.0000x reference)
//
#include <hip/hip_runtime.h>
#include <hip/hip_bf16.h>
#include <hip/hip_fp16.h>
#include <hip/hip_fp8.h>
#include <math.h>

typedef __hip_bfloat16 bf16;
typedef __attribute__((ext_vector_type(8))) short short8;
typedef __attribute__((ext_vector_type(4))) float f32x4;

#define NPB   65536   // positions per batch (16*64*64)
#define DIMC  48
#define C2    192
#define HIDC  96
#define TT    16

static __device__ __forceinline__ float b2f(bf16 v) { return __bfloat162float(v); }
static __device__ __forceinline__ bf16  f2b(float v) { return __float2bfloat16(v); }
static __device__ __forceinline__ float bfr2f(unsigned short u) {
  union { unsigned int i; float f; } c; c.i = ((unsigned int)u) << 16; return c.f;
}
static __device__ __forceinline__ unsigned short f2us(float v) {
  return __bfloat16_as_ushort(__float2bfloat16(v));
}
static __device__ __forceinline__ unsigned char f2fp8(float v) {
  __hip_fp8_e4m3 t(v); return (unsigned char)t.__x;
}
static __device__ __forceinline__ float fp82f(unsigned char u) {
  __hip_fp8_e4m3 t; t.__x = (__hip_fp8_storage_t)u; return (float)t;
}

// ---- hardware fp8 packed converts (gfx950: OCP e4m3fn, matches __hip_fp8_e4m3) --
#if defined(__has_builtin)
#if __has_builtin(__builtin_amdgcn_cvt_pk_f32_fp8) && __has_builtin(__builtin_amdgcn_cvt_pk_fp8_f32)
#define HW_FP8 1
#endif
#endif

// decode 4 packed fp8 bytes -> 4 f32 (2 HW insts)
static __device__ __forceinline__ void fp8x4_to_f32x4(unsigned int u, float* o) {
#ifdef HW_FP8
  auto lo = __builtin_amdgcn_cvt_pk_f32_fp8(u, false);
  auto hi = __builtin_amdgcn_cvt_pk_f32_fp8(u, true);
  o[0] = lo[0]; o[1] = lo[1]; o[2] = hi[0]; o[3] = hi[1];
#else
  o[0] = fp82f(u & 0xff); o[1] = fp82f((u >> 8) & 0xff);
  o[2] = fp82f((u >> 16) & 0xff); o[3] = fp82f((u >> 24) & 0xff);
#endif
}
// encode 2 f32 -> 2 fp8 bytes in low word (1 HW inst)
static __device__ __forceinline__ unsigned int f32x2_to_fp8pair(float x, float y) {
#ifdef HW_FP8
  return (unsigned int)__builtin_amdgcn_cvt_pk_fp8_f32(x, y, 0, false) & 0xffffu;
#else
  return (unsigned int)f2fp8(x) | ((unsigned int)f2fp8(y) << 8);
#endif
}
// decode the low-word fp8 pair -> 2 f32 (1 HW inst)
static __device__ __forceinline__ void fp8pair_to_2f(unsigned int pr, float& x, float& y) {
#ifdef HW_FP8
  auto d = __builtin_amdgcn_cvt_pk_f32_fp8(pr, false);
  x = d[0]; y = d[1];
#else
  x = fp82f(pr & 0xff); y = fp82f((pr >> 8) & 0xff);
#endif
}

// pack two f32 -> half2 (u32), single v_cvt_pkrtz_f16_f32 (exact for fp8-decoded vals)
static __device__ __forceinline__ unsigned int pkh2(float x, float y) {
  auto h = __builtin_amdgcn_cvt_pkrtz(x, y);   // __fp16 ext_vector_type(2)
  return __builtin_bit_cast(unsigned int, h);
}
// dual f16 multiply, f32 accumulate: acc += a.lo*b.lo + a.hi*b.hi
static __device__ __forceinline__ float dot2f16(unsigned int a, unsigned int b, float c) {
  asm("v_dot2_f32_f16 %0, %1, %2, %0" : "+v"(c) : "v"(a), "v"(b));
  return c;
}
static __device__ __forceinline__ __half2 u2h2(unsigned int u) {
  return __builtin_bit_cast(__half2, u);
}
// LDS chunk swizzle (8B chunks): XOR bits 0-2 with bits 4-6 — makes both the
// staging b8 writes (lane-stride 8 chunks) and fragment b64 reads (lane-stride
// 2 chunks) bank-conflict-free. Bijective within 128-chunk windows.
static __device__ __forceinline__ int swz8(int c) { return c ^ ((c >> 4) & 7); }

// ---------------- y = LN(x) over 48 channels, bf16 out (LN1 and LN2) -------------
__global__ __launch_bounds__(256) void k_ln(
    const float* __restrict__ x, const float* __restrict__ lw, const float* __restrict__ lb,
    bf16* __restrict__ y) {
  int p = blockIdx.x * 256 + threadIdx.x;   // 0..131071
  int b = p >> 16, n = p & (NPB - 1);
  const float* xb = x + ((size_t)b * DIMC) * NPB + n;
  float v[DIMC]; float s = 0.f, s2 = 0.f;
#pragma unroll
  for (int c = 0; c < DIMC; ++c) { float t = xb[(size_t)c * NPB]; v[c] = t; s += t; s2 += t * t; }
  float mu = s * (1.f / DIMC);
  float var = fmaxf(s2 * (1.f / DIMC) - mu * mu, 0.f);
  float rs = rsqrtf(var + 1e-5f);
  bf16* yb = y + ((size_t)b * DIMC) * NPB + n;
#pragma unroll
  for (int c = 0; c < DIMC; ++c) yb[(size_t)c * NPB] = f2b((v[c] - mu) * rs * lw[c] + lb[c]);
}

// ------- MFMA 1x1 conv, sectioned, fp8(x16) out. grid (NSEC, 1024) ----------------
// hp >= 0: qkv head-pair mapping (sec 0..5 -> q(2hp),q(2hp+1),k0,k1,v0,v1)
// hp <  0: plain rows sec*48 (FFN pin).
// Epilogue: fp8 bytes staged to Ot[48][132] (LDS), then full-line uchar4 stores.
__global__ __launch_bounds__(256) void k_pconv_sec(
    const bf16* __restrict__ y, const float* __restrict__ W,
    const float* __restrict__ bias, int hp, unsigned char* __restrict__ dst, int dcs) {
  __shared__ unsigned short Yl[64][130];
  __shared__ unsigned short Wl[48][72];
  __shared__ unsigned char Ot[48][132];
  int tid = threadIdx.x;
  int sec = blockIdx.x;
  int row = (hp >= 0) ? ((sec >> 1) * 192 + (2 * hp + (sec & 1)) * 48) : sec * 48;
  int bt = blockIdx.y;
  int b = bt >> 9;
  int n0 = (bt & 511) * 128;
  const unsigned short* yb = (const unsigned short*)(y + ((size_t)b * DIMC) * NPB) + n0;
  for (int j = tid; j < 48 * 32; j += 256) {       // stage Y (48 x 128)
    int c = j >> 5, sub = j & 31;
    ushort4 u = *(const ushort4*)(yb + (size_t)c * NPB + sub * 4);
    *(ushort2*)&Yl[c][sub * 4]     = make_ushort2(u.x, u.y);
    *(ushort2*)&Yl[c][sub * 4 + 2] = make_ushort2(u.z, u.w);
  }
  for (int j = tid; j < 16 * 32; j += 256) {       // zero rows 48..63
    int c = 48 + (j >> 5), sub = j & 31;
    *(ushort2*)&Yl[c][sub * 4]     = make_ushort2(0, 0);
    *(ushort2*)&Yl[c][sub * 4 + 2] = make_ushort2(0, 0);
  }
  if (tid < 48) {
    const float* wr = W + (size_t)(row + tid) * 48;
    unsigned short* wl = Wl[tid];
#pragma unroll
    for (int c = 0; c < 48; ++c) wl[c] = f2us(wr[c]);
#pragma unroll
    for (int c = 48; c < 64; ++c) wl[c] = 0;
  }
  __syncthreads();
  int wv = tid >> 6, ln = tid & 63, lq = ln >> 4, li = ln & 15;
  short8 afr[3][2];
#pragma unroll
  for (int mt = 0; mt < 3; ++mt)
#pragma unroll
    for (int ks = 0; ks < 2; ++ks)
      afr[mt][ks] = *(const short8*)&Wl[mt * 16 + li][ks * 32 + lq * 8];
#pragma unroll 1
  for (int ns = 0; ns < 2; ++ns) {
    int nn = wv * 32 + ns * 16 + li;
    short8 bfr[2];
#pragma unroll
    for (int ks = 0; ks < 2; ++ks)
#pragma unroll
      for (int j = 0; j < 8; ++j)
        bfr[ks][j] = (short)Yl[ks * 32 + lq * 8 + j][nn];
#pragma unroll
    for (int mt = 0; mt < 3; ++mt) {
      f32x4 acc = {0.f, 0.f, 0.f, 0.f};
      acc = __builtin_amdgcn_mfma_f32_16x16x32_bf16(afr[mt][0], bfr[0], acc, 0, 0, 0);
      acc = __builtin_amdgcn_mfma_f32_16x16x32_bf16(afr[mt][1], bfr[1], acc, 0, 0, 0);
      int m0 = mt * 16 + lq * 4;
      unsigned int p01 = f32x2_to_fp8pair(16.f * (acc[0] + bias[row + m0]),
                                          16.f * (acc[1] + bias[row + m0 + 1]));
      unsigned int p23 = f32x2_to_fp8pair(16.f * (acc[2] + bias[row + m0 + 2]),
                                          16.f * (acc[3] + bias[row + m0 + 3]));
      Ot[m0 + 0][nn] = (unsigned char)p01;
      Ot[m0 + 1][nn] = (unsigned char)(p01 >> 8);
      Ot[m0 + 2][nn] = (unsigned char)p23;
      Ot[m0 + 3][nn] = (unsigned char)(p23 >> 8);
    }
  }
  __syncthreads();
  for (int j = tid; j < 48 * 32; j += 256) {       // full-line stores
    int m = j >> 5, c4 = (j & 31) * 4;
    *(uchar4*)(dst + ((size_t)b * dcs + sec * 48 + m) * NPB + n0 + c4) =
        *(const uchar4*)&Ot[m][c4];
  }
}

// ------- grouped 3x3x3 conv via MFMA: C[pos16][oc16], K=32={2tap x 16ch} ----------
// grid (64, NCB, 2): x = t-tile(8) x h-tile(8) [2t x 8h x 64w], y = 16-oc block.
// 512 thr (8 waves). Tile: [4tt][10hh][66ww][16ch] fp8, 8B-chunk-swizzled (42KB,
// 3 blocks/CU). Weights (block-diag 4x4) in 56 VGPRs. 14 mfma_16x16x32_f16 per
// 16-pos tile (27 taps + 1 zero). A-frag: ds_read_b64 + HW fp8->f16 decode.
// Output bounced through reused-LDS Ot for full-line stores + sumsq.
__global__ __launch_bounds__(512, 4) void k_gconv48(
    const unsigned char* __restrict__ src, int sco,
    const float* __restrict__ gw, const float* __restrict__ gb,
    unsigned char* __restrict__ dst, int hp, int isV, float* __restrict__ sqout) {
  __shared__ unsigned char lds[42240];   // 2640 cells x 16 ch; reused as Ot[16][1040]
  int tid = threadIdx.x;
  int t0 = (blockIdx.x >> 3) * 2, h0 = (blockIdx.x & 7) * 8;
  int cb = blockIdx.y * 16, b = blockIdx.z;
  int seg = cb / 48, lc = cb - seg * 48;
  int wbase = isV ? 384 + (2 * hp + seg) * 48 + lc
                  : ((seg >= 2 ? 192 : 0) + (2 * hp + (seg & 1)) * 48 + lc);
  int dch = isV ? (2 * hp + seg) * 48 + lc : cb;
  const unsigned char* ib = src + ((size_t)b * 288 + sco + cb) * NPB;

  // ---- stage tile (fp8, chunk-swizzled) ----
#pragma unroll 1
  for (int ch = 0; ch < 16; ++ch) {
    const unsigned char* chp = ib + (size_t)ch * NPB;
    int hi = ch >> 3, lo = ch & 7;
    for (int j = tid; j < 640; j += 512) {        // 4tt x 10hh x 16sub
      int tt = j / 160, rem = j - tt * 160, hh = rem >> 4, sub = rem & 15;
      int gt = t0 + tt - 1, gh = h0 + hh - 1;
      uchar4 u = make_uchar4(0, 0, 0, 0);
      if ((unsigned)gt < 16u && (unsigned)gh < 64u)
        u = *(const uchar4*)(chp + (size_t)gt * 4096 + gh * 64 + sub * 4);
      int cell = (tt * 10 + hh) * 66 + 1 + sub * 4;
      lds[swz8((cell + 0) * 2 + hi) * 8 + lo] = u.x;
      lds[swz8((cell + 1) * 2 + hi) * 8 + lo] = u.y;
      lds[swz8((cell + 2) * 2 + hi) * 8 + lo] = u.z;
      lds[swz8((cell + 3) * 2 + hi) * 8 + lo] = u.w;
    }
  }
  for (int j = tid; j < 160; j += 512) {          // ww halos (0, 65): zero chunks
    int half = j & 1, side = (j >> 1) & 1, r = j >> 2;   // r: 0..39
    int tt = r / 10, hh = r - tt * 10;
    int cell = (tt * 10 + hh) * 66 + (side ? 65 : 0);
    *(unsigned long long*)&lds[swz8(cell * 2 + half) * 8] = 0ull;
  }

  // ---- B fragments (weights) -> 14 short8 regs ----
  int ln = tid & 63, li = ln & 15, lq = ln >> 4;
  int g4 = (li >> 2) * 4;                          // group input-ch base (block-local)
  int chb = (lq & 1) * 8;
  int lqh = lq >> 1;
  const float* wrow = gw + (size_t)(wbase + li) * 108;
  short8 bw[14];
#pragma unroll
  for (int p = 0; p < 14; ++p) {
    int tap = 2 * p + lqh;
    union { unsigned int u[4]; short8 s; } cv;
#pragma unroll
    for (int jj = 0; jj < 4; ++jj) {
      int ch0 = chb + jj * 2, ch1 = ch0 + 1;
      float f0 = (tap < 27 && ch0 >= g4 && ch0 < g4 + 4) ? wrow[(ch0 - g4) * 27 + tap] : 0.f;
      float f1 = (tap < 27 && ch1 >= g4 && ch1 < g4 + 4) ? wrow[(ch1 - g4) * 27 + tap] : 0.f;
      cv.u[jj] = pkh2(f0, f1);
    }
    bw[p] = cv.s;
  }
  __syncthreads();

  // ---- conv: 8 pos-tiles/wave x 14 MFMA ----
  int wvv = tid >> 6;
  unsigned int outp[8];
  float bias16 = 16.f * gb[wbase + li];
#pragma unroll 1
  for (int tl = 0; tl < 8; ++tl) {
    int tile_id = wvv * 8 + tl;
    int t_o = tile_id >> 5, h_o = (tile_id >> 2) & 7, w0 = (tile_id & 3) << 4;
    int cbase = (t_o * 10 + h_o) * 66 + w0 + li;
    f32x4 acc = {0.f, 0.f, 0.f, 0.f};
#pragma unroll
    for (int p = 0; p < 14; ++p) {
      int tA = 2 * p, tB = 2 * p + 1;
      int offA = ((tA / 9) * 10 + (tA % 9) / 3) * 66 + tA % 3;
      int offB = (tB < 27) ? (((tB / 9) * 10 + (tB % 9) / 3) * 66 + tB % 3) : 0;
      int off = (lqh ? offB : offA);
      short8 af;
      if (2 * p + lqh < 27) {
        int c = (cbase + off) * 2 + (lq & 1);
        uint2 raw = *(const uint2*)&lds[swz8(c) * 8];
        float f[8];
        fp8x4_to_f32x4(raw.x, f);
        fp8x4_to_f32x4(raw.y, f + 4);
        union { unsigned int u[4]; short8 s; } cv;
        cv.u[0] = pkh2(f[0], f[1]); cv.u[1] = pkh2(f[2], f[3]);
        cv.u[2] = pkh2(f[4], f[5]); cv.u[3] = pkh2(f[6], f[7]);
        af = cv.s;
      } else {
        af = (short8){0, 0, 0, 0, 0, 0, 0, 0};
      }
      acc = __builtin_amdgcn_mfma_f32_16x16x32_f16(af, bw[p], acc, 0, 0, 0);
    }
    // lane holds C[w = w0 + lq*4 + r][oc = li], r=0..3 -> one u32 of 4 fp8
    unsigned int p01 = f32x2_to_fp8pair(acc[0] + bias16, acc[1] + bias16);
    unsigned int p23 = f32x2_to_fp8pair(acc[2] + bias16, acc[3] + bias16);
    outp[tl] = (p01 & 0xffffu) | (p23 << 16);
  }
  __syncthreads();                                // conv reads done -> reuse LDS as Ot
#pragma unroll
  for (int tl = 0; tl < 8; ++tl) {
    int tile_id = wvv * 8 + tl;
    int t_o = tile_id >> 5, h_o = (tile_id >> 2) & 7, w0 = (tile_id & 3) << 4;
    int pos = t_o * 512 + h_o * 64 + w0 + lq * 4;
    *(unsigned int*)&lds[li * 1040 + pos] = outp[tl];
  }
  __syncthreads();
  // ---- cooperative full-line store + sumsq ----
  int oc = tid >> 5, lp = tid & 31;
  size_t obase = ((size_t)b * 192 + dch + oc) * NPB;
  float s = 0.f;
#pragma unroll
  for (int k2 = 0; k2 < 8; ++k2) {
    int pos = (lp + k2 * 32) * 4;
    unsigned int v = *(const unsigned int*)&lds[oc * 1040 + pos];
    int t = pos >> 9, h = (pos >> 6) & 7, w = pos & 63;
    *(unsigned int*)(dst + obase + (size_t)(t0 + t) * 4096 + (h0 + h) * 64 + w) = v;
    if (sqout) {
      float f[4]; fp8x4_to_f32x4(v, f);
      s += f[0] * f[0] + f[1] * f[1] + f[2] * f[2] + f[3] * f[3];
    }
  }
  if (sqout) {
#pragma unroll
    for (int off = 16; off; off >>= 1) s += __shfl_down(s, off, 32);
    if (lp == 0) {
      int sqi = (seg < 2 ? 0 : 384) + b * 192 + (2 * hp + (seg & 1)) * 48 + lc + oc;
      atomicAdd(&sqout[sqi], s);
    }
  }
}

// ---------------- MFMA Gram from fp8 q,k (x16): scale cancels with norms ----------
// grid (64, 2, 2): x = 1024-wide n-chunk, y = batch, z = head-in-pair.
__global__ __launch_bounds__(256) void k_gram_mfma(
    const unsigned char* __restrict__ qkd, int hp, float* __restrict__ Gm) {
  __shared__ unsigned short qkl[2][48][264];
  int tid = threadIdx.x, b = blockIdx.y, z = blockIdx.z;
  int wv = tid >> 6, ln = tid & 63, lq = ln >> 4, li = ln & 15;
  const unsigned char* qb = qkd + ((size_t)b * 192 + z * 48) * NPB + blockIdx.x * 1024;
  const unsigned char* kb = qkd + ((size_t)b * 192 + 96 + z * 48) * NPB + blockIdx.x * 1024;
  f32x4 acc[9];
#pragma unroll
  for (int t = 0; t < 9; ++t) acc[t] = (f32x4){0.f, 0.f, 0.f, 0.f};
#pragma unroll 1
  for (int it = 0; it < 4; ++it) {
    __syncthreads();
    for (int j = tid; j < 48 * 64; j += 256) {
      int c = j >> 6, sub = j & 63;
      unsigned int uq = *(const unsigned int*)(qb + (size_t)c * NPB + it * 256 + sub * 4);
      unsigned int uk = *(const unsigned int*)(kb + (size_t)c * NPB + it * 256 + sub * 4);
      float aq[4], ak[4];
      fp8x4_to_f32x4(uq, aq);
      fp8x4_to_f32x4(uk, ak);
      *(ushort2*)&qkl[0][c][sub * 4]     = make_ushort2(f2us(aq[0]), f2us(aq[1]));
      *(ushort2*)&qkl[0][c][sub * 4 + 2] = make_ushort2(f2us(aq[2]), f2us(aq[3]));
      *(ushort2*)&qkl[1][c][sub * 4]     = make_ushort2(f2us(ak[0]), f2us(ak[1]));
      *(ushort2*)&qkl[1][c][sub * 4 + 2] = make_ushort2(f2us(ak[2]), f2us(ak[3]));
    }
    __syncthreads();
    short8 afr[3][2], bfr[3][2];
#pragma unroll
    for (int ks = 0; ks < 2; ++ks) {
      int kbase = wv * 64 + ks * 32 + lq * 8;
#pragma unroll
      for (int t = 0; t < 3; ++t) {
        afr[t][ks] = *(const short8*)&qkl[0][t * 16 + li][kbase];
        bfr[t][ks] = *(const short8*)&qkl[1][t * 16 + li][kbase];
      }
    }
#pragma unroll
    for (int mt = 0; mt < 3; ++mt)
#pragma unroll
      for (int nt = 0; nt < 3; ++nt) {
        acc[mt * 3 + nt] = __builtin_amdgcn_mfma_f32_16x16x32_bf16(afr[mt][0], bfr[nt][0], acc[mt * 3 + nt], 0, 0, 0);
        acc[mt * 3 + nt] = __builtin_amdgcn_mfma_f32_16x16x32_bf16(afr[mt][1], bfr[nt][1], acc[mt * 3 + nt], 0, 0, 0);
      }
  }
  __syncthreads();
  float* red = (float*)&qkl[0][0][0];
  if (wv > 0) {
    float* rw = red + (size_t)(wv - 1) * 2304;
#pragma unroll
    for (int t = 0; t < 9; ++t)
#pragma unroll
      for (int r = 0; r < 4; ++r)
        rw[t * 256 + r * 64 + ln] = acc[t][r];
  }
  __syncthreads();
  if (wv == 0) {
    int hd = 2 * hp + z;
    float* gbase = Gm + (size_t)(b * 4 + hd) * 2304;
#pragma unroll
    for (int t = 0; t < 9; ++t) {
      int mt = t / 3, nt = t - mt * 3;
#pragma unroll
      for (int r = 0; r < 4; ++r) {
        int o = t * 256 + r * 64 + ln;
        float v = acc[t][r] + red[o] + red[2304 + o] + red[4608 + o];
        atomicAdd(&gbase[(mt * 16 + lq * 4 + r) * 48 + nt * 16 + li], v);
      }
    }
  }
}

// ------- tiny: per-(b,head) softmax(norm G) + proj fold -> Mm[b][48][192] bf16 ----
__global__ __launch_bounds__(256) void k_attn_mm(
    const float* __restrict__ Gm, const float* __restrict__ sq, const float* __restrict__ temp,
    const float* __restrict__ pw, bf16* __restrict__ Mm) {
  __shared__ float A[48][48];
  __shared__ float nk[48];
  int tid = threadIdx.x;
  int bh = blockIdx.x; int b = bh >> 2, hd = bh & 3;
  if (tid >= 64 && tid < 112)
    nk[tid - 64] = fmaxf(sqrtf(sq[384 + bh * 48 + tid - 64]), 1e-12f);
  __syncthreads();
  if (tid < 48) {
    float tv = temp[hd];
    float rq = 1.f / fmaxf(sqrtf(sq[bh * 48 + tid]), 1e-12f);
    const float* grow = Gm + (size_t)bh * 2304 + tid * 48;
    float mx = -1e30f;
#pragma unroll
    for (int d = 0; d < 48; ++d) mx = fmaxf(mx, grow[d] * rq / nk[d] * tv);
    float sum = 0.f;
#pragma unroll
    for (int d = 0; d < 48; ++d) {
      float e = expf(grow[d] * rq / nk[d] * tv - mx);
      A[tid][d] = e; sum += e;
    }
    float inv = 1.f / sum;
#pragma unroll
    for (int d = 0; d < 48; ++d) A[tid][d] *= inv;
  }
  __syncthreads();
  for (int j = tid; j < 2304; j += 256) {
    int m = j / 48, d = j - m * 48;
    float a = 0.f;
#pragma unroll
    for (int c = 0; c < 48; ++c) a = fmaf(pw[m * 192 + hd * 48 + c], A[c][d], a);
    Mm[((size_t)b * 48 + m) * 192 + hd * 48 + d] = f2b(a * 0.0625f);
  }
}

// ------- K=192 GEMM: out = x + pb + Mm[b] @ v8[b]  (fp8 v, bf16 MFMA) -------------
__global__ __launch_bounds__(256) void k_av192(
    const unsigned char* __restrict__ vd8, const bf16* __restrict__ Mm,
    const float* __restrict__ pb, const float* __restrict__ x, float* __restrict__ outp) {
  __shared__ unsigned short Yl[96][130];
  __shared__ unsigned short Ml[48][200];
  int tid = threadIdx.x;
  int bt = blockIdx.x;
  int b = bt >> 9;
  int n0 = (bt & 511) * 128;
  int wv = tid >> 6, ln = tid & 63, lq = ln >> 4, li = ln & 15;
  const unsigned short* mb = (const unsigned short*)(Mm + (size_t)b * 48 * 192);
  for (int j = tid; j < 48 * 48; j += 256) {       // stage M (48 x 192)
    int m = j / 48, c4 = j - m * 48;
    *(ushort4*)&Ml[m][c4 * 4] = *(const ushort4*)(mb + m * 192 + c4 * 4);
  }
  const unsigned char* vb = vd8 + ((size_t)b * C2) * NPB + n0;
  f32x4 acc[3][2];
#pragma unroll
  for (int mt = 0; mt < 3; ++mt)
#pragma unroll
    for (int ns = 0; ns < 2; ++ns) acc[mt][ns] = (f32x4){0.f, 0.f, 0.f, 0.f};
#pragma unroll 1
  for (int s = 0; s < 2; ++s) {
    __syncthreads();
    for (int j = tid; j < 96 * 32; j += 256) {     // stage V half (96 x 128), decode
      int c = j >> 5, sub = j & 31;
      unsigned int u = *(const unsigned int*)(vb + (size_t)(s * 96 + c) * NPB + sub * 4);
      float a[4]; fp8x4_to_f32x4(u, a);
      *(ushort2*)&Yl[c][sub * 4]     = make_ushort2(f2us(a[0]), f2us(a[1]));
      *(ushort2*)&Yl[c][sub * 4 + 2] = make_ushort2(f2us(a[2]), f2us(a[3]));
    }
    __syncthreads();
#pragma unroll 1
    for (int ns = 0; ns < 2; ++ns) {
      int nn = wv * 32 + ns * 16 + li;
      short8 bfr[3];
#pragma unroll
      for (int ks = 0; ks < 3; ++ks)
#pragma unroll
        for (int j = 0; j < 8; ++j)
          bfr[ks][j] = (short)Yl[ks * 32 + lq * 8 + j][nn];
#pragma unroll
      for (int mt = 0; mt < 3; ++mt) {
        short8 a0 = *(const short8*)&Ml[mt * 16 + li][s * 96 + lq * 8];
        short8 a1 = *(const short8*)&Ml[mt * 16 + li][s * 96 + 32 + lq * 8];
        short8 a2 = *(const short8*)&Ml[mt * 16 + li][s * 96 + 64 + lq * 8];
        acc[mt][ns] = __builtin_amdgcn_mfma_f32_16x16x32_bf16(a0, bfr[0], acc[mt][ns], 0, 0, 0);
        acc[mt][ns] = __builtin_amdgcn_mfma_f32_16x16x32_bf16(a1, bfr[1], acc[mt][ns], 0, 0, 0);
        acc[mt][ns] = __builtin_amdgcn_mfma_f32_16x16x32_bf16(a2, bfr[2], acc[mt][ns], 0, 0, 0);
      }
    }
  }
#pragma unroll
  for (int ns = 0; ns < 2; ++ns) {
    int nn = wv * 32 + ns * 16 + li;
#pragma unroll
    for (int mt = 0; mt < 3; ++mt)
#pragma unroll
      for (int r = 0; r < 4; ++r) {
        int m = mt * 16 + lq * 4 + r;
        size_t idx = ((size_t)b * DIMC + m) * NPB + n0 + nn;
        outp[idx] = x[idx] + pb[m] + acc[mt][ns][r];
      }
  }
}

// ---------------- MFMA K=96 GEMM (pout), fp8(x16) input: out = addend+bias+W@g ----
__global__ __launch_bounds__(256) void k_ek96(
    const unsigned char* __restrict__ V, const float* __restrict__ W, int wrs,
    const float* __restrict__ bias, const float* __restrict__ addend, float* __restrict__ outp) {
  __shared__ unsigned short Yl[96][130];
  __shared__ unsigned short Wl[48][104];
  int tid = threadIdx.x;
  int bt = blockIdx.x;
  int b = bt >> 9;
  int n0 = (bt & 511) * 128;
  const unsigned char* vb = V + ((size_t)b * 96) * NPB + n0;
  for (int j = tid; j < 96 * 32; j += 256) {
    int c = j >> 5, sub = j & 31;
    unsigned int u = *(const unsigned int*)(vb + (size_t)c * NPB + sub * 4);
    float a[4]; fp8x4_to_f32x4(u, a);
    *(ushort2*)&Yl[c][sub * 4]     = make_ushort2(f2us(a[0]), f2us(a[1]));
    *(ushort2*)&Yl[c][sub * 4 + 2] = make_ushort2(f2us(a[2]), f2us(a[3]));
  }
  if (tid < 48) {
    const float* wr = W + (size_t)tid * wrs;
    unsigned short* wl = Wl[tid];
#pragma unroll
    for (int c = 0; c < 96; ++c) wl[c] = f2us(wr[c] * 0.0625f);   // cancel x16
  }
  __syncthreads();
  int wv = tid >> 6, ln = tid & 63, lq = ln >> 4, li = ln & 15;
  short8 afr[3][3];
#pragma unroll
  for (int mt = 0; mt < 3; ++mt)
#pragma unroll
    for (int ks = 0; ks < 3; ++ks)
      afr[mt][ks] = *(const short8*)&Wl[mt * 16 + li][ks * 32 + lq * 8];
#pragma unroll 1
  for (int ns = 0; ns < 2; ++ns) {
    int nn = wv * 32 + ns * 16 + li;
    short8 bfr[3];
#pragma unroll
    for (int ks = 0; ks < 3; ++ks)
#pragma unroll
      for (int j = 0; j < 8; ++j)
        bfr[ks][j] = (short)Yl[ks * 32 + lq * 8 + j][nn];
#pragma unroll
    for (int mt = 0; mt < 3; ++mt) {
      f32x4 acc = {0.f, 0.f, 0.f, 0.f};
      acc = __builtin_amdgcn_mfma_f32_16x16x32_bf16(afr[mt][0], bfr[0], acc, 0, 0, 0);
      acc = __builtin_amdgcn_mfma_f32_16x16x32_bf16(afr[mt][1], bfr[1], acc, 0, 0, 0);
      acc = __builtin_amdgcn_mfma_f32_16x16x32_bf16(afr[mt][2], bfr[2], acc, 0, 0, 0);
#pragma unroll
      for (int r = 0; r < 4; ++r) {
        int m = mt * 16 + lq * 4 + r;
        size_t idx = ((size_t)b * DIMC + m) * NPB + n0 + nn;
        outp[idx] = acc[r] + addend[idx] + bias[m];
      }
    }
  }
}

// ------- depthwise 3x3x3 + GELU gate; ch-pair half2 tile, ONE staging pass --------
// grid (32, 96, 2): x = t-tile(8) x h-tile(4) [2t x 16h x 64w], y = ch pair (c,c+96).
__global__ __launch_bounds__(256) void k_dw_gelu(
    const unsigned char* __restrict__ z, const float* __restrict__ dwW,
    const float* __restrict__ dwB, unsigned char* __restrict__ g) {
  __shared__ unsigned int tile[4][18][68];   // 19,584 B; row stride 272B
  int tid = threadIdx.x;
  int t0 = (blockIdx.x >> 2) * 2, h0 = (blockIdx.x & 3) * 16;
  int c = blockIdx.y, b = blockIdx.z;
  int wq = tid & 15, hq = tid >> 4;      // wq: w-quad, hq: h-row 0..15
  int w0 = wq * 4;
  const unsigned char* zp0 = z + ((size_t)b * C2 + c) * NPB;
  const unsigned char* zp1 = zp0 + (size_t)HIDC * NPB;
  for (int j = tid; j < 72 * 16; j += 256) {     // stage 4tt x 18hh x 64w, both ch
    int r = j >> 4, sub = j & 15;
    int tt = r / 18, hh = r - tt * 18;
    int gt = t0 + tt - 1, gh = h0 + hh - 1;
    unsigned int* dp = &tile[tt][hh][1 + sub * 4];
    if ((unsigned)gt < 16u && (unsigned)gh < 64u) {
      size_t off = (size_t)gt * 4096 + gh * 64 + sub * 4;
      unsigned int u0 = *(const unsigned int*)(zp0 + off);
      unsigned int u1 = *(const unsigned int*)(zp1 + off);
      float a0[4], a1[4];
      fp8x4_to_f32x4(u0, a0);
      fp8x4_to_f32x4(u1, a1);
      dp[0] = pkh2(a0[0], a1[0]);
      dp[1] = pkh2(a0[1], a1[1]);
      dp[2] = pkh2(a0[2], a1[2]);
      dp[3] = pkh2(a0[3], a1[3]);
    } else { dp[0] = 0; dp[1] = 0; dp[2] = 0; dp[3] = 0; }
  }
  for (int j = tid; j < 144; j += 256) {         // w halos
    int r = j >> 1, side = j & 1;
    int tt = r / 18, hh = r - tt * 18;
    tile[tt][hh][side ? 65 : 0] = 0;
  }
  // pack weight pairs {w_c[tap], w_c96[tap]} (uniform per block)
  unsigned int wpk[27];
  {
    const float* wt0 = dwW + (size_t)c * 27;
    const float* wt1 = dwW + (size_t)(c + HIDC) * 27;
#pragma unroll
    for (int tap = 0; tap < 27; ++tap) wpk[tap] = pkh2(wt0[tap], wt1[tap]);
  }
  __syncthreads();
  __half2 hacc[2][4];                            // [t][k] {sum_c, sum_c96}
#pragma unroll
  for (int t = 0; t < 2; ++t)
#pragma unroll
    for (int k = 0; k < 4; ++k) hacc[t][k] = u2h2(0u);
#pragma unroll 1
  for (int dh = 0; dh < 3; ++dh) {
    unsigned int v[4][6];                        // rows hq+dh, cols w0..w0+5
#pragma unroll
    for (int tt = 0; tt < 4; ++tt) {
      uint4 q4 = *(const uint4*)&tile[tt][hq + dh][w0];
      uint2 q2 = *(const uint2*)&tile[tt][hq + dh][w0 + 4];
      v[tt][0] = q4.x; v[tt][1] = q4.y; v[tt][2] = q4.z; v[tt][3] = q4.w;
      v[tt][4] = q2.x; v[tt][5] = q2.y;
    }
#pragma unroll
    for (int dt = 0; dt < 3; ++dt)
#pragma unroll
      for (int dw = 0; dw < 3; ++dw) {
        __half2 wk = u2h2(wpk[dt * 9 + dh * 3 + dw]);
#pragma unroll
        for (int t = 0; t < 2; ++t)
#pragma unroll
          for (int k = 0; k < 4; ++k)
            hacc[t][k] = __hfma2(u2h2(v[t + dt][dw + k]), wk, hacc[t][k]);
      }
  }
  float b1 = dwB[c], b2v = dwB[c + HIDC];
  size_t obase = ((size_t)b * HIDC + c) * NPB;
#pragma unroll
  for (int t = 0; t < 2; ++t) {
    float e[4];
#pragma unroll
    for (int k = 0; k < 4; ++k) {
      float x1v = __low2float(hacc[t][k]) * 0.0625f + b1;
      float x2v = __high2float(hacc[t][k]) * 0.0625f + b2v;
      float ge = 0.5f * x1v * (1.f + erff(x1v * 0.70710678118654752f));
      e[k] = 16.f * ge * x2v;
    }
    unsigned int p01 = f32x2_to_fp8pair(e[0], e[1]);
    unsigned int p23 = f32x2_to_fp8pair(e[2], e[3]);
    unsigned int packed = p01 | (p23 << 16);
    *(unsigned int*)(g + obase + (t0 + t) * 4096 + (h0 + hq) * 64 + w0) = packed;
  }
}

extern "C" void kernel_launch(void* const* d_in, const int* in_sizes, int n_in,
                              void* d_out, int out_size, void* d_ws, size_t ws_size,
                              hipStream_t stream) {
  (void)in_sizes; (void)n_in; (void)out_size; (void)ws_size;
  const float* x     = (const float*)d_in[0];
  const float* ln1w  = (const float*)d_in[1];
  const float* ln1b  = (const float*)d_in[2];
  const float* qkvw  = (const float*)d_in[3];
  const float* qkvb  = (const float*)d_in[4];
  const float* gdww  = (const float*)d_in[5];
  const float* gdwb  = (const float*)d_in[6];
  const float* temp  = (const float*)d_in[7];
  const float* projw = (const float*)d_in[8];
  const float* projb = (const float*)d_in[9];
  const float* ln2w  = (const float*)d_in[10];
  const float* ln2b  = (const float*)d_in[11];
  const float* pinw  = (const float*)d_in[12];
  const float* pinb  = (const float*)d_in[13];
  const float* dww   = (const float*)d_in[14];
  const float* dwb   = (const float*)d_in[15];
  const float* poutw = (const float*)d_in[16];
  const float* poutb = (const float*)d_in[17];
  float* out = (float*)d_out;

  // Workspace: y 12.6M | st288 37.7M | vd8 25.2M | Gm/sq/Mm tail -> 75.61M (proven)
  // qkd8 lives in d_out (exactly 25,165,824 B), dead before k_av192 writes out.
  char* ws = (char*)d_ws;
  bf16*  y     = (bf16*)(ws);                              // 12,582,912 B
  unsigned char* st288 = (unsigned char*)(ws + 12582912);  // 37,748,736 B [2][288][NPB]
  unsigned char* vd8   = (unsigned char*)(ws + 50331648);  // 25,165,824 B [2][192][NPB]
  float* Gm    = (float*)(ws + 75497472);                  //     73,728 B
  float* sq    = (float*)(ws + 75571200);                  //      3,072 B
  bf16*  Mm    = (bf16*)(ws + 75574272);                   //     36,864 B
  unsigned char* qkd8 = (unsigned char*)d_out;             // 25,165,824 B (scratch)
  // FFN phase (attention buffers dead):
  bf16*  y2    = (bf16*)(ws);                              // 12,582,912 B
  unsigned char* z8  = (unsigned char*)(ws + 12582912);    // 25,165,824 B
  unsigned char* gg8 = (unsigned char*)(ws + 37748736);    // 12,582,912 B

  (void)hipMemsetAsync(Gm, 0, 73728 + 3072, stream);
  k_ln<<<dim3(512), dim3(256), 0, stream>>>(x, ln1w, ln1b, y);

  for (int hp = 0; hp < 2; ++hp) {
    // q,k,v pointwise for head pair (6 sections), fp8 out -> st288
    k_pconv_sec<<<dim3(6, 1024), dim3(256), 0, stream>>>(y, qkvw, qkvb, hp, st288, 288);
    // grouped dw-conv q+k (192 ch = 12 x 16-oc blocks) -> qkd8 (in d_out) + sumsq
    k_gconv48<<<dim3(64, 12, 2), dim3(512), 0, stream>>>(
        st288, 0, gdww, gdwb, qkd8, hp, 0, sq);
    // Gram for both heads of the pair
    k_gram_mfma<<<dim3(64, 2, 2), dim3(256), 0, stream>>>(qkd8, hp, Gm);
    // grouped dw-conv v (96 ch = 6 x 16-oc blocks) -> vd8 slots
    k_gconv48<<<dim3(64, 6, 2), dim3(512), 0, stream>>>(
        st288, 192, gdww, gdwb, vd8, hp, 1, nullptr);
  }
  k_attn_mm<<<dim3(8), dim3(256), 0, stream>>>(Gm, sq, temp, projw, Mm);
  k_av192<<<dim3(1024), dim3(256), 0, stream>>>(vd8, Mm, projb, x, out);

  k_ln<<<dim3(512), dim3(256), 0, stream>>>(out, ln2w, ln2b, y2);
  k_pconv_sec<<<dim3(4, 1024), dim3(256), 0, stream>>>(y2, pinw, pinb, -1, z8, 192);
  k_dw_gelu<<<dim3(32, 96, 2), dim3(256), 0, stream>>>(z8, dww, dwb, gg8);
  k_ek96<<<dim3(1024), dim3(256), 0, stream>>>(gg8, poutw, 96, poutb, out, out);
}

// Round 11
// 594.639 us; speedup vs baseline: 1.1250x; 1.1250x over previous
//
#include <hip/hip_runtime.h>
#include <hip/hip_bf16.h>
#include <hip/hip_fp16.h>
#include <hip/hip_fp8.h>
#include <math.h>

typedef __hip_bfloat16 bf16;
typedef __attribute__((ext_vector_type(8))) short short8;
typedef __attribute__((ext_vector_type(4))) float f32x4;

#define NPB   65536   // positions per batch (16*64*64)
#define DIMC  48
#define C2    192
#define HIDC  96
#define TT    16

static __device__ __forceinline__ float b2f(bf16 v) { return __bfloat162float(v); }
static __device__ __forceinline__ bf16  f2b(float v) { return __float2bfloat16(v); }
static __device__ __forceinline__ float bfr2f(unsigned short u) {
  union { unsigned int i; float f; } c; c.i = ((unsigned int)u) << 16; return c.f;
}
static __device__ __forceinline__ unsigned short f2us(float v) {
  return __bfloat16_as_ushort(__float2bfloat16(v));
}
static __device__ __forceinline__ unsigned char f2fp8(float v) {
  __hip_fp8_e4m3 t(v); return (unsigned char)t.__x;
}
static __device__ __forceinline__ float fp82f(unsigned char u) {
  __hip_fp8_e4m3 t; t.__x = (__hip_fp8_storage_t)u; return (float)t;
}

// ---- hardware fp8 packed converts (gfx950: OCP e4m3fn, matches __hip_fp8_e4m3) --
#if defined(__has_builtin)
#if __has_builtin(__builtin_amdgcn_cvt_pk_f32_fp8) && __has_builtin(__builtin_amdgcn_cvt_pk_fp8_f32)
#define HW_FP8 1
#endif
#endif

// decode 4 packed fp8 bytes -> 4 f32 (2 HW insts)
static __device__ __forceinline__ void fp8x4_to_f32x4(unsigned int u, float* o) {
#ifdef HW_FP8
  auto lo = __builtin_amdgcn_cvt_pk_f32_fp8(u, false);
  auto hi = __builtin_amdgcn_cvt_pk_f32_fp8(u, true);
  o[0] = lo[0]; o[1] = lo[1]; o[2] = hi[0]; o[3] = hi[1];
#else
  o[0] = fp82f(u & 0xff); o[1] = fp82f((u >> 8) & 0xff);
  o[2] = fp82f((u >> 16) & 0xff); o[3] = fp82f((u >> 24) & 0xff);
#endif
}
// encode 2 f32 -> 2 fp8 bytes in low word (1 HW inst)
static __device__ __forceinline__ unsigned int f32x2_to_fp8pair(float x, float y) {
#ifdef HW_FP8
  return (unsigned int)__builtin_amdgcn_cvt_pk_fp8_f32(x, y, 0, false) & 0xffffu;
#else
  return (unsigned int)f2fp8(x) | ((unsigned int)f2fp8(y) << 8);
#endif
}
// decode the low-word fp8 pair -> 2 f32 (1 HW inst)
static __device__ __forceinline__ void fp8pair_to_2f(unsigned int pr, float& x, float& y) {
#ifdef HW_FP8
  auto d = __builtin_amdgcn_cvt_pk_f32_fp8(pr, false);
  x = d[0]; y = d[1];
#else
  x = fp82f(pr & 0xff); y = fp82f((pr >> 8) & 0xff);
#endif
}

// pack two f32 -> half2 (u32), single v_cvt_pkrtz_f16_f32 (exact for fp8-decoded vals)
static __device__ __forceinline__ unsigned int pkh2(float x, float y) {
  auto h = __builtin_amdgcn_cvt_pkrtz(x, y);   // __fp16 ext_vector_type(2)
  return __builtin_bit_cast(unsigned int, h);
}
// dual f16 multiply, f32 accumulate: acc += a.lo*b.lo + a.hi*b.hi
static __device__ __forceinline__ float dot2f16(unsigned int a, unsigned int b, float c) {
  asm("v_dot2_f32_f16 %0, %1, %2, %0" : "+v"(c) : "v"(a), "v"(b));
  return c;
}
static __device__ __forceinline__ __half2 u2h2(unsigned int u) {
  return __builtin_bit_cast(__half2, u);
}
// LDS chunk swizzle (8B chunks): XOR bits 0-2 with bits 4-6 (validated in R9).
static __device__ __forceinline__ int swz8(int c) { return c ^ ((c >> 4) & 7); }

// ---------------- y = LN(x) over 48 channels, bf16 out (LN1 and LN2) -------------
__global__ __launch_bounds__(256) void k_ln(
    const float* __restrict__ x, const float* __restrict__ lw, const float* __restrict__ lb,
    bf16* __restrict__ y) {
  int p = blockIdx.x * 256 + threadIdx.x;   // 0..131071
  int b = p >> 16, n = p & (NPB - 1);
  const float* xb = x + ((size_t)b * DIMC) * NPB + n;
  float v[DIMC]; float s = 0.f, s2 = 0.f;
#pragma unroll
  for (int c = 0; c < DIMC; ++c) { float t = xb[(size_t)c * NPB]; v[c] = t; s += t; s2 += t * t; }
  float mu = s * (1.f / DIMC);
  float var = fmaxf(s2 * (1.f / DIMC) - mu * mu, 0.f);
  float rs = rsqrtf(var + 1e-5f);
  bf16* yb = y + ((size_t)b * DIMC) * NPB + n;
#pragma unroll
  for (int c = 0; c < DIMC; ++c) yb[(size_t)c * NPB] = f2b((v[c] - mu) * rs * lw[c] + lb[c]);
}

// ------- MFMA 1x1 conv, sectioned, fp8(x16) out. grid (NSEC, 1024) ----------------
__global__ __launch_bounds__(256) void k_pconv_sec(
    const bf16* __restrict__ y, const float* __restrict__ W,
    const float* __restrict__ bias, int hp, unsigned char* __restrict__ dst, int dcs) {
  __shared__ unsigned short Yl[64][130];
  __shared__ unsigned short Wl[48][72];
  __shared__ unsigned char Ot[48][132];
  int tid = threadIdx.x;
  int sec = blockIdx.x;
  int row = (hp >= 0) ? ((sec >> 1) * 192 + (2 * hp + (sec & 1)) * 48) : sec * 48;
  int bt = blockIdx.y;
  int b = bt >> 9;
  int n0 = (bt & 511) * 128;
  const unsigned short* yb = (const unsigned short*)(y + ((size_t)b * DIMC) * NPB) + n0;
  for (int j = tid; j < 48 * 32; j += 256) {       // stage Y (48 x 128)
    int c = j >> 5, sub = j & 31;
    ushort4 u = *(const ushort4*)(yb + (size_t)c * NPB + sub * 4);
    *(ushort2*)&Yl[c][sub * 4]     = make_ushort2(u.x, u.y);
    *(ushort2*)&Yl[c][sub * 4 + 2] = make_ushort2(u.z, u.w);
  }
  for (int j = tid; j < 16 * 32; j += 256) {       // zero rows 48..63
    int c = 48 + (j >> 5), sub = j & 31;
    *(ushort2*)&Yl[c][sub * 4]     = make_ushort2(0, 0);
    *(ushort2*)&Yl[c][sub * 4 + 2] = make_ushort2(0, 0);
  }
  if (tid < 48) {
    const float* wr = W + (size_t)(row + tid) * 48;
    unsigned short* wl = Wl[tid];
#pragma unroll
    for (int c = 0; c < 48; ++c) wl[c] = f2us(wr[c]);
#pragma unroll
    for (int c = 48; c < 64; ++c) wl[c] = 0;
  }
  __syncthreads();
  int wv = tid >> 6, ln = tid & 63, lq = ln >> 4, li = ln & 15;
  short8 afr[3][2];
#pragma unroll
  for (int mt = 0; mt < 3; ++mt)
#pragma unroll
    for (int ks = 0; ks < 2; ++ks)
      afr[mt][ks] = *(const short8*)&Wl[mt * 16 + li][ks * 32 + lq * 8];
#pragma unroll 1
  for (int ns = 0; ns < 2; ++ns) {
    int nn = wv * 32 + ns * 16 + li;
    short8 bfr[2];
#pragma unroll
    for (int ks = 0; ks < 2; ++ks)
#pragma unroll
      for (int j = 0; j < 8; ++j)
        bfr[ks][j] = (short)Yl[ks * 32 + lq * 8 + j][nn];
#pragma unroll
    for (int mt = 0; mt < 3; ++mt) {
      f32x4 acc = {0.f, 0.f, 0.f, 0.f};
      acc = __builtin_amdgcn_mfma_f32_16x16x32_bf16(afr[mt][0], bfr[0], acc, 0, 0, 0);
      acc = __builtin_amdgcn_mfma_f32_16x16x32_bf16(afr[mt][1], bfr[1], acc, 0, 0, 0);
      int m0 = mt * 16 + lq * 4;
      unsigned int p01 = f32x2_to_fp8pair(16.f * (acc[0] + bias[row + m0]),
                                          16.f * (acc[1] + bias[row + m0 + 1]));
      unsigned int p23 = f32x2_to_fp8pair(16.f * (acc[2] + bias[row + m0 + 2]),
                                          16.f * (acc[3] + bias[row + m0 + 3]));
      Ot[m0 + 0][nn] = (unsigned char)p01;
      Ot[m0 + 1][nn] = (unsigned char)(p01 >> 8);
      Ot[m0 + 2][nn] = (unsigned char)p23;
      Ot[m0 + 3][nn] = (unsigned char)(p23 >> 8);
    }
  }
  __syncthreads();
  for (int j = tid; j < 48 * 32; j += 256) {       // full-line stores
    int m = j >> 5, c4 = (j & 31) * 4;
    *(uchar4*)(dst + ((size_t)b * dcs + sec * 48 + m) * NPB + n0 + c4) =
        *(const uchar4*)&Ot[m][c4];
  }
}

// ------- grouped 3x3x3 conv via fp8 MFMA: C[pos16][oc16], K=32={2tap x 16ch} ------
// grid (64, NCB, 2). 512 thr (8 waves). Tile [4tt][10hh][66ww]x16ch fp8, swz8 chunks
// (layout validated by R9 run). A-frag = RAW ds_read_b64 (no decode!). Weights fp8
// two-term split: w = hi + res/16 (2 MFMA/frag vs same A) -> weight err ~0.4% << fp8
// activation quant. Staging: register 4x4 byte transpose (v_perm) + b32 writes.
__global__ __launch_bounds__(512, 4) void k_gconv48(
    const unsigned char* __restrict__ src, int sco,
    const float* __restrict__ gw, const float* __restrict__ gb,
    unsigned char* __restrict__ dst, int hp, int isV, float* __restrict__ sqout) {
  __shared__ unsigned char lds[42240];   // 2640 cells x 16 ch; reused as Ot[16][1040]
  int tid = threadIdx.x;
  int t0 = (blockIdx.x >> 3) * 2, h0 = (blockIdx.x & 7) * 8;
  int cb = blockIdx.y * 16, b = blockIdx.z;
  int seg = cb / 48, lc = cb - seg * 48;
  int wbase = isV ? 384 + (2 * hp + seg) * 48 + lc
                  : ((seg >= 2 ? 192 : 0) + (2 * hp + (seg & 1)) * 48 + lc);
  int dch = isV ? (2 * hp + seg) * 48 + lc : cb;
  const unsigned char* ib = src + ((size_t)b * 288 + sco + cb) * NPB;

  // ---- stage tile: 4-ch quads, register byte-transpose, b32 swizzled writes ----
#pragma unroll 1
  for (int cq = 0; cq < 4; ++cq) {
    const unsigned char* c0p = ib + (size_t)(cq * 4) * NPB;
    for (int j = tid; j < 640; j += 512) {        // 4tt x 10hh x 16sub
      int tt = j / 160, rem = j - tt * 160, hh = rem >> 4, sub = rem & 15;
      int gt = t0 + tt - 1, gh = h0 + hh - 1;
      unsigned int u0 = 0, u1 = 0, u2 = 0, u3 = 0;
      if ((unsigned)gt < 16u && (unsigned)gh < 64u) {
        size_t off = (size_t)gt * 4096 + gh * 64 + sub * 4;
        u0 = *(const unsigned int*)(c0p + off);
        u1 = *(const unsigned int*)(c0p + NPB + off);
        u2 = *(const unsigned int*)(c0p + 2 * (size_t)NPB + off);
        u3 = *(const unsigned int*)(c0p + 3 * (size_t)NPB + off);
      }
      int cell0 = (tt * 10 + hh) * 66 + 1 + sub * 4;
#pragma unroll
      for (int j2 = 0; j2 < 4; ++j2) {
        unsigned int selp = 0x0c0c0000u | ((unsigned)(4 + j2) << 8) | (unsigned)j2;
        unsigned int p01 = __builtin_amdgcn_perm(u1, u0, selp);
        unsigned int p23 = __builtin_amdgcn_perm(u3, u2, selp);
        unsigned int o = __builtin_amdgcn_perm(p23, p01, 0x05040100u);
        int cell = cell0 + j2;
        *(unsigned int*)&lds[swz8(cell * 2 + (cq >> 1)) * 8 + (cq & 1) * 4] = o;
      }
    }
  }
  for (int j = tid; j < 160; j += 512) {          // ww halos (0, 65): zero chunks
    int half = j & 1, side = (j >> 1) & 1, r = j >> 2;   // r: 0..39
    int tt = r / 10, hh = r - tt * 10;
    int cell = (tt * 10 + hh) * 66 + (side ? 65 : 0);
    *(unsigned long long*)&lds[swz8(cell * 2 + half) * 8] = 0ull;
  }

  // ---- B fragments: fp8 weights, hi + residual(x16) -> 28 longs ----
  int ln = tid & 63, li = ln & 15, lq = ln >> 4;
  int lqh = lq >> 1, chalf = lq & 1;
  int g4 = (li >> 2) * 4;                          // group input-ch base (block-local)
  const float* wrow = gw + (size_t)(wbase + li) * 108;
  long bhi[14], bres[14];
#pragma unroll
  for (int p = 0; p < 14; ++p) {
    int tap = 2 * p + lqh;
    unsigned int uh[2], ur[2];
#pragma unroll
    for (int hf = 0; hf < 2; ++hf) {
      unsigned int ph = 0, pr = 0;
#pragma unroll
      for (int q = 0; q < 2; ++q) {
        int ch0 = chalf * 8 + hf * 4 + q * 2, ch1 = ch0 + 1;
        float w0v = 0.f, w1v = 0.f;
        if (tap < 27) {
          if (ch0 >= g4 && ch0 < g4 + 4) w0v = wrow[(ch0 - g4) * 27 + tap];
          if (ch1 >= g4 && ch1 < g4 + 4) w1v = wrow[(ch1 - g4) * 27 + tap];
        }
        unsigned int hp8 = f32x2_to_fp8pair(w0v, w1v);
        float d0, d1; fp8pair_to_2f(hp8, d0, d1);
        unsigned int rp8 = f32x2_to_fp8pair((w0v - d0) * 16.f, (w1v - d1) * 16.f);
        ph |= hp8 << (16 * q);
        pr |= rp8 << (16 * q);
      }
      uh[hf] = ph; ur[hf] = pr;
    }
    uint2 th = {uh[0], uh[1]}, tr = {ur[0], ur[1]};
    bhi[p]  = __builtin_bit_cast(long, th);
    bres[p] = __builtin_bit_cast(long, tr);
  }
  __syncthreads();

  // ---- conv: 8 pos-tiles/wave x (14 raw b64 reads + 28 fp8 MFMA) ----
  int wvv = tid >> 6;
  unsigned int outp8[8];
  float bias16 = 16.f * gb[wbase + li];
#pragma unroll 1
  for (int tl = 0; tl < 8; ++tl) {
    int tile_id = wvv * 8 + tl;
    int t_o = tile_id >> 5, h_o = (tile_id >> 2) & 7, w0 = (tile_id & 3) << 4;
    int cbase = (t_o * 10 + h_o) * 66 + w0 + li;
    f32x4 ah = {0.f, 0.f, 0.f, 0.f}, ar = {0.f, 0.f, 0.f, 0.f};
#pragma unroll
    for (int p = 0; p < 14; ++p) {
      int tA = 2 * p, tB = 2 * p + 1;
      int offA = ((tA / 9) * 10 + (tA % 9) / 3) * 66 + tA % 3;
      int offB = (tB < 27) ? (((tB / 9) * 10 + (tB % 9) / 3) * 66 + tB % 3) : 0;
      int off = lqh ? offB : offA;
      int c = (cbase + off) * 2 + chalf;
      uint2 raw = *(const uint2*)&lds[swz8(c) * 8];
      long a = __builtin_bit_cast(long, raw);
      ah = __builtin_amdgcn_mfma_f32_16x16x32_fp8_fp8(a, bhi[p], ah, 0, 0, 0);
      ar = __builtin_amdgcn_mfma_f32_16x16x32_fp8_fp8(a, bres[p], ar, 0, 0, 0);
    }
    unsigned int p01 = f32x2_to_fp8pair(ah[0] + ar[0] * 0.0625f + bias16,
                                        ah[1] + ar[1] * 0.0625f + bias16);
    unsigned int p23 = f32x2_to_fp8pair(ah[2] + ar[2] * 0.0625f + bias16,
                                        ah[3] + ar[3] * 0.0625f + bias16);
    outp8[tl] = (p01 & 0xffffu) | (p23 << 16);
  }
  __syncthreads();                                // conv reads done -> reuse LDS as Ot
#pragma unroll
  for (int tl = 0; tl < 8; ++tl) {
    int tile_id = wvv * 8 + tl;
    int t_o = tile_id >> 5, h_o = (tile_id >> 2) & 7, w0 = (tile_id & 3) << 4;
    int pos = t_o * 512 + h_o * 64 + w0 + lq * 4;
    *(unsigned int*)&lds[li * 1040 + pos] = outp8[tl];
  }
  __syncthreads();
  // ---- cooperative full-line store + sumsq ----
  int oc = tid >> 5, lp = tid & 31;
  size_t obase = ((size_t)b * 192 + dch + oc) * NPB;
  float s = 0.f;
#pragma unroll
  for (int k2 = 0; k2 < 8; ++k2) {
    int pos = (lp + k2 * 32) * 4;
    unsigned int v = *(const unsigned int*)&lds[oc * 1040 + pos];
    int t = pos >> 9, h = (pos >> 6) & 7, w = pos & 63;
    *(unsigned int*)(dst + obase + (size_t)(t0 + t) * 4096 + (h0 + h) * 64 + w) = v;
    if (sqout) {
      float f[4]; fp8x4_to_f32x4(v, f);
      s += f[0] * f[0] + f[1] * f[1] + f[2] * f[2] + f[3] * f[3];
    }
  }
  if (sqout) {
#pragma unroll
    for (int off = 16; off; off >>= 1) s += __shfl_down(s, off, 32);
    if (lp == 0) {
      int sqi = (seg < 2 ? 0 : 384) + b * 192 + (2 * hp + (seg & 1)) * 48 + lc + oc;
      atomicAdd(&sqout[sqi], s);
    }
  }
}

// ---------------- MFMA Gram from fp8 q,k (x16): scale cancels with norms ----------
__global__ __launch_bounds__(256) void k_gram_mfma(
    const unsigned char* __restrict__ qkd, int hp, float* __restrict__ Gm) {
  __shared__ unsigned short qkl[2][48][264];
  int tid = threadIdx.x, b = blockIdx.y, z = blockIdx.z;
  int wv = tid >> 6, ln = tid & 63, lq = ln >> 4, li = ln & 15;
  const unsigned char* qb = qkd + ((size_t)b * 192 + z * 48) * NPB + blockIdx.x * 1024;
  const unsigned char* kb = qkd + ((size_t)b * 192 + 96 + z * 48) * NPB + blockIdx.x * 1024;
  f32x4 acc[9];
#pragma unroll
  for (int t = 0; t < 9; ++t) acc[t] = (f32x4){0.f, 0.f, 0.f, 0.f};
#pragma unroll 1
  for (int it = 0; it < 4; ++it) {
    __syncthreads();
    for (int j = tid; j < 48 * 64; j += 256) {
      int c = j >> 6, sub = j & 63;
      unsigned int uq = *(const unsigned int*)(qb + (size_t)c * NPB + it * 256 + sub * 4);
      unsigned int uk = *(const unsigned int*)(kb + (size_t)c * NPB + it * 256 + sub * 4);
      float aq[4], ak[4];
      fp8x4_to_f32x4(uq, aq);
      fp8x4_to_f32x4(uk, ak);
      *(ushort2*)&qkl[0][c][sub * 4]     = make_ushort2(f2us(aq[0]), f2us(aq[1]));
      *(ushort2*)&qkl[0][c][sub * 4 + 2] = make_ushort2(f2us(aq[2]), f2us(aq[3]));
      *(ushort2*)&qkl[1][c][sub * 4]     = make_ushort2(f2us(ak[0]), f2us(ak[1]));
      *(ushort2*)&qkl[1][c][sub * 4 + 2] = make_ushort2(f2us(ak[2]), f2us(ak[3]));
    }
    __syncthreads();
    short8 afr[3][2], bfr[3][2];
#pragma unroll
    for (int ks = 0; ks < 2; ++ks) {
      int kbase = wv * 64 + ks * 32 + lq * 8;
#pragma unroll
      for (int t = 0; t < 3; ++t) {
        afr[t][ks] = *(const short8*)&qkl[0][t * 16 + li][kbase];
        bfr[t][ks] = *(const short8*)&qkl[1][t * 16 + li][kbase];
      }
    }
#pragma unroll
    for (int mt = 0; mt < 3; ++mt)
#pragma unroll
      for (int nt = 0; nt < 3; ++nt) {
        acc[mt * 3 + nt] = __builtin_amdgcn_mfma_f32_16x16x32_bf16(afr[mt][0], bfr[nt][0], acc[mt * 3 + nt], 0, 0, 0);
        acc[mt * 3 + nt] = __builtin_amdgcn_mfma_f32_16x16x32_bf16(afr[mt][1], bfr[nt][1], acc[mt * 3 + nt], 0, 0, 0);
      }
  }
  __syncthreads();
  float* red = (float*)&qkl[0][0][0];
  if (wv > 0) {
    float* rw = red + (size_t)(wv - 1) * 2304;
#pragma unroll
    for (int t = 0; t < 9; ++t)
#pragma unroll
      for (int r = 0; r < 4; ++r)
        rw[t * 256 + r * 64 + ln] = acc[t][r];
  }
  __syncthreads();
  if (wv == 0) {
    int hd = 2 * hp + z;
    float* gbase = Gm + (size_t)(b * 4 + hd) * 2304;
#pragma unroll
    for (int t = 0; t < 9; ++t) {
      int mt = t / 3, nt = t - mt * 3;
#pragma unroll
      for (int r = 0; r < 4; ++r) {
        int o = t * 256 + r * 64 + ln;
        float v = acc[t][r] + red[o] + red[2304 + o] + red[4608 + o];
        atomicAdd(&gbase[(mt * 16 + lq * 4 + r) * 48 + nt * 16 + li], v);
      }
    }
  }
}

// ------- tiny: per-(b,head) softmax(norm G) + proj fold -> Mm[b][48][192] bf16 ----
__global__ __launch_bounds__(256) void k_attn_mm(
    const float* __restrict__ Gm, const float* __restrict__ sq, const float* __restrict__ temp,
    const float* __restrict__ pw, bf16* __restrict__ Mm) {
  __shared__ float A[48][48];
  __shared__ float nk[48];
  int tid = threadIdx.x;
  int bh = blockIdx.x; int b = bh >> 2, hd = bh & 3;
  if (tid >= 64 && tid < 112)
    nk[tid - 64] = fmaxf(sqrtf(sq[384 + bh * 48 + tid - 64]), 1e-12f);
  __syncthreads();
  if (tid < 48) {
    float tv = temp[hd];
    float rq = 1.f / fmaxf(sqrtf(sq[bh * 48 + tid]), 1e-12f);
    const float* grow = Gm + (size_t)bh * 2304 + tid * 48;
    float mx = -1e30f;
#pragma unroll
    for (int d = 0; d < 48; ++d) mx = fmaxf(mx, grow[d] * rq / nk[d] * tv);
    float sum = 0.f;
#pragma unroll
    for (int d = 0; d < 48; ++d) {
      float e = expf(grow[d] * rq / nk[d] * tv - mx);
      A[tid][d] = e; sum += e;
    }
    float inv = 1.f / sum;
#pragma unroll
    for (int d = 0; d < 48; ++d) A[tid][d] *= inv;
  }
  __syncthreads();
  for (int j = tid; j < 2304; j += 256) {
    int m = j / 48, d = j - m * 48;
    float a = 0.f;
#pragma unroll
    for (int c = 0; c < 48; ++c) a = fmaf(pw[m * 192 + hd * 48 + c], A[c][d], a);
    Mm[((size_t)b * 48 + m) * 192 + hd * 48 + d] = f2b(a * 0.0625f);
  }
}

// ------- K=192 GEMM: out = x + pb + Mm[b] @ v8[b]  (fp8 v, bf16 MFMA) -------------
__global__ __launch_bounds__(256) void k_av192(
    const unsigned char* __restrict__ vd8, const bf16* __restrict__ Mm,
    const float* __restrict__ pb, const float* __restrict__ x, float* __restrict__ outp) {
  __shared__ unsigned short Yl[96][130];
  __shared__ unsigned short Ml[48][200];
  int tid = threadIdx.x;
  int bt = blockIdx.x;
  int b = bt >> 9;
  int n0 = (bt & 511) * 128;
  int wv = tid >> 6, ln = tid & 63, lq = ln >> 4, li = ln & 15;
  const unsigned short* mb = (const unsigned short*)(Mm + (size_t)b * 48 * 192);
  for (int j = tid; j < 48 * 48; j += 256) {       // stage M (48 x 192)
    int m = j / 48, c4 = j - m * 48;
    *(ushort4*)&Ml[m][c4 * 4] = *(const ushort4*)(mb + m * 192 + c4 * 4);
  }
  const unsigned char* vb = vd8 + ((size_t)b * C2) * NPB + n0;
  f32x4 acc[3][2];
#pragma unroll
  for (int mt = 0; mt < 3; ++mt)
#pragma unroll
    for (int ns = 0; ns < 2; ++ns) acc[mt][ns] = (f32x4){0.f, 0.f, 0.f, 0.f};
#pragma unroll 1
  for (int s = 0; s < 2; ++s) {
    __syncthreads();
    for (int j = tid; j < 96 * 32; j += 256) {     // stage V half (96 x 128), decode
      int c = j >> 5, sub = j & 31;
      unsigned int u = *(const unsigned int*)(vb + (size_t)(s * 96 + c) * NPB + sub * 4);
      float a[4]; fp8x4_to_f32x4(u, a);
      *(ushort2*)&Yl[c][sub * 4]     = make_ushort2(f2us(a[0]), f2us(a[1]));
      *(ushort2*)&Yl[c][sub * 4 + 2] = make_ushort2(f2us(a[2]), f2us(a[3]));
    }
    __syncthreads();
#pragma unroll 1
    for (int ns = 0; ns < 2; ++ns) {
      int nn = wv * 32 + ns * 16 + li;
      short8 bfr[3];
#pragma unroll
      for (int ks = 0; ks < 3; ++ks)
#pragma unroll
        for (int j = 0; j < 8; ++j)
          bfr[ks][j] = (short)Yl[ks * 32 + lq * 8 + j][nn];
#pragma unroll
      for (int mt = 0; mt < 3; ++mt) {
        short8 a0 = *(const short8*)&Ml[mt * 16 + li][s * 96 + lq * 8];
        short8 a1 = *(const short8*)&Ml[mt * 16 + li][s * 96 + 32 + lq * 8];
        short8 a2 = *(const short8*)&Ml[mt * 16 + li][s * 96 + 64 + lq * 8];
        acc[mt][ns] = __builtin_amdgcn_mfma_f32_16x16x32_bf16(a0, bfr[0], acc[mt][ns], 0, 0, 0);
        acc[mt][ns] = __builtin_amdgcn_mfma_f32_16x16x32_bf16(a1, bfr[1], acc[mt][ns], 0, 0, 0);
        acc[mt][ns] = __builtin_amdgcn_mfma_f32_16x16x32_bf16(a2, bfr[2], acc[mt][ns], 0, 0, 0);
      }
    }
  }
#pragma unroll
  for (int ns = 0; ns < 2; ++ns) {
    int nn = wv * 32 + ns * 16 + li;
#pragma unroll
    for (int mt = 0; mt < 3; ++mt)
#pragma unroll
      for (int r = 0; r < 4; ++r) {
        int m = mt * 16 + lq * 4 + r;
        size_t idx = ((size_t)b * DIMC + m) * NPB + n0 + nn;
        outp[idx] = x[idx] + pb[m] + acc[mt][ns][r];
      }
  }
}

// ---------------- MFMA K=96 GEMM (pout), fp8(x16) input: out = addend+bias+W@g ----
__global__ __launch_bounds__(256) void k_ek96(
    const unsigned char* __restrict__ V, const float* __restrict__ W, int wrs,
    const float* __restrict__ bias, const float* __restrict__ addend, float* __restrict__ outp) {
  __shared__ unsigned short Yl[96][130];
  __shared__ unsigned short Wl[48][104];
  int tid = threadIdx.x;
  int bt = blockIdx.x;
  int b = bt >> 9;
  int n0 = (bt & 511) * 128;
  const unsigned char* vb = V + ((size_t)b * 96) * NPB + n0;
  for (int j = tid; j < 96 * 32; j += 256) {
    int c = j >> 5, sub = j & 31;
    unsigned int u = *(const unsigned int*)(vb + (size_t)c * NPB + sub * 4);
    float a[4]; fp8x4_to_f32x4(u, a);
    *(ushort2*)&Yl[c][sub * 4]     = make_ushort2(f2us(a[0]), f2us(a[1]));
    *(ushort2*)&Yl[c][sub * 4 + 2] = make_ushort2(f2us(a[2]), f2us(a[3]));
  }
  if (tid < 48) {
    const float* wr = W + (size_t)tid * wrs;
    unsigned short* wl = Wl[tid];
#pragma unroll
    for (int c = 0; c < 96; ++c) wl[c] = f2us(wr[c] * 0.0625f);   // cancel x16
  }
  __syncthreads();
  int wv = tid >> 6, ln = tid & 63, lq = ln >> 4, li = ln & 15;
  short8 afr[3][3];
#pragma unroll
  for (int mt = 0; mt < 3; ++mt)
#pragma unroll
    for (int ks = 0; ks < 3; ++ks)
      afr[mt][ks] = *(const short8*)&Wl[mt * 16 + li][ks * 32 + lq * 8];
#pragma unroll 1
  for (int ns = 0; ns < 2; ++ns) {
    int nn = wv * 32 + ns * 16 + li;
    short8 bfr[3];
#pragma unroll
    for (int ks = 0; ks < 3; ++ks)
#pragma unroll
      for (int j = 0; j < 8; ++j)
        bfr[ks][j] = (short)Yl[ks * 32 + lq * 8 + j][nn];
#pragma unroll
    for (int mt = 0; mt < 3; ++mt) {
      f32x4 acc = {0.f, 0.f, 0.f, 0.f};
      acc = __builtin_amdgcn_mfma_f32_16x16x32_bf16(afr[mt][0], bfr[0], acc, 0, 0, 0);
      acc = __builtin_amdgcn_mfma_f32_16x16x32_bf16(afr[mt][1], bfr[1], acc, 0, 0, 0);
      acc = __builtin_amdgcn_mfma_f32_16x16x32_bf16(afr[mt][2], bfr[2], acc, 0, 0, 0);
#pragma unroll
      for (int r = 0; r < 4; ++r) {
        int m = mt * 16 + lq * 4 + r;
        size_t idx = ((size_t)b * DIMC + m) * NPB + n0 + nn;
        outp[idx] = acc[r] + addend[idx] + bias[m];
      }
    }
  }
}

// ------- depthwise 3x3x3 + GELU gate; ch-pair half2 tile, ONE staging pass --------
__global__ __launch_bounds__(256) void k_dw_gelu(
    const unsigned char* __restrict__ z, const float* __restrict__ dwW,
    const float* __restrict__ dwB, unsigned char* __restrict__ g) {
  __shared__ unsigned int tile[4][18][68];   // 19,584 B; row stride 272B
  int tid = threadIdx.x;
  int t0 = (blockIdx.x >> 2) * 2, h0 = (blockIdx.x & 3) * 16;
  int c = blockIdx.y, b = blockIdx.z;
  int wq = tid & 15, hq = tid >> 4;      // wq: w-quad, hq: h-row 0..15
  int w0 = wq * 4;
  const unsigned char* zp0 = z + ((size_t)b * C2 + c) * NPB;
  const unsigned char* zp1 = zp0 + (size_t)HIDC * NPB;
  for (int j = tid; j < 72 * 16; j += 256) {     // stage 4tt x 18hh x 64w, both ch
    int r = j >> 4, sub = j & 15;
    int tt = r / 18, hh = r - tt * 18;
    int gt = t0 + tt - 1, gh = h0 + hh - 1;
    unsigned int* dp = &tile[tt][hh][1 + sub * 4];
    if ((unsigned)gt < 16u && (unsigned)gh < 64u) {
      size_t off = (size_t)gt * 4096 + gh * 64 + sub * 4;
      unsigned int u0 = *(const unsigned int*)(zp0 + off);
      unsigned int u1 = *(const unsigned int*)(zp1 + off);
      float a0[4], a1[4];
      fp8x4_to_f32x4(u0, a0);
      fp8x4_to_f32x4(u1, a1);
      dp[0] = pkh2(a0[0], a1[0]);
      dp[1] = pkh2(a0[1], a1[1]);
      dp[2] = pkh2(a0[2], a1[2]);
      dp[3] = pkh2(a0[3], a1[3]);
    } else { dp[0] = 0; dp[1] = 0; dp[2] = 0; dp[3] = 0; }
  }
  for (int j = tid; j < 144; j += 256) {         // w halos
    int r = j >> 1, side = j & 1;
    int tt = r / 18, hh = r - tt * 18;
    tile[tt][hh][side ? 65 : 0] = 0;
  }
  // pack weight pairs {w_c[tap], w_c96[tap]} (uniform per block)
  unsigned int wpk[27];
  {
    const float* wt0 = dwW + (size_t)c * 27;
    const float* wt1 = dwW + (size_t)(c + HIDC) * 27;
#pragma unroll
    for (int tap = 0; tap < 27; ++tap) wpk[tap] = pkh2(wt0[tap], wt1[tap]);
  }
  __syncthreads();
  __half2 hacc[2][4];                            // [t][k] {sum_c, sum_c96}
#pragma unroll
  for (int t = 0; t < 2; ++t)
#pragma unroll
    for (int k = 0; k < 4; ++k) hacc[t][k] = u2h2(0u);
#pragma unroll 1
  for (int dh = 0; dh < 3; ++dh) {
    unsigned int v[4][6];                        // rows hq+dh, cols w0..w0+5
#pragma unroll
    for (int tt = 0; tt < 4; ++tt) {
      uint4 q4 = *(const uint4*)&tile[tt][hq + dh][w0];
      uint2 q2 = *(const uint2*)&tile[tt][hq + dh][w0 + 4];
      v[tt][0] = q4.x; v[tt][1] = q4.y; v[tt][2] = q4.z; v[tt][3] = q4.w;
      v[tt][4] = q2.x; v[tt][5] = q2.y;
    }
#pragma unroll
    for (int dt = 0; dt < 3; ++dt)
#pragma unroll
      for (int dw = 0; dw < 3; ++dw) {
        __half2 wk = u2h2(wpk[dt * 9 + dh * 3 + dw]);
#pragma unroll
        for (int t = 0; t < 2; ++t)
#pragma unroll
          for (int k = 0; k < 4; ++k)
            hacc[t][k] = __hfma2(u2h2(v[t + dt][dw + k]), wk, hacc[t][k]);
      }
  }
  float b1 = dwB[c], b2v = dwB[c + HIDC];
  size_t obase = ((size_t)b * HIDC + c) * NPB;
#pragma unroll
  for (int t = 0; t < 2; ++t) {
    float e[4];
#pragma unroll
    for (int k = 0; k < 4; ++k) {
      float x1v = __low2float(hacc[t][k]) * 0.0625f + b1;
      float x2v = __high2float(hacc[t][k]) * 0.0625f + b2v;
      float ge = 0.5f * x1v * (1.f + erff(x1v * 0.70710678118654752f));
      e[k] = 16.f * ge * x2v;
    }
    unsigned int p01 = f32x2_to_fp8pair(e[0], e[1]);
    unsigned int p23 = f32x2_to_fp8pair(e[2], e[3]);
    unsigned int packed = p01 | (p23 << 16);
    *(unsigned int*)(g + obase + (t0 + t) * 4096 + (h0 + hq) * 64 + w0) = packed;
  }
}

extern "C" void kernel_launch(void* const* d_in, const int* in_sizes, int n_in,
                              void* d_out, int out_size, void* d_ws, size_t ws_size,
                              hipStream_t stream) {
  (void)in_sizes; (void)n_in; (void)out_size; (void)ws_size;
  const float* x     = (const float*)d_in[0];
  const float* ln1w  = (const float*)d_in[1];
  const float* ln1b  = (const float*)d_in[2];
  const float* qkvw  = (const float*)d_in[3];
  const float* qkvb  = (const float*)d_in[4];
  const float* gdww  = (const float*)d_in[5];
  const float* gdwb  = (const float*)d_in[6];
  const float* temp  = (const float*)d_in[7];
  const float* projw = (const float*)d_in[8];
  const float* projb = (const float*)d_in[9];
  const float* ln2w  = (const float*)d_in[10];
  const float* ln2b  = (const float*)d_in[11];
  const float* pinw  = (const float*)d_in[12];
  const float* pinb  = (const float*)d_in[13];
  const float* dww   = (const float*)d_in[14];
  const float* dwb   = (const float*)d_in[15];
  const float* poutw = (const float*)d_in[16];
  const float* poutb = (const float*)d_in[17];
  float* out = (float*)d_out;

  // Workspace: y 12.6M | st288 37.7M | vd8 25.2M | Gm/sq/Mm tail -> 75.61M (proven)
  // qkd8 lives in d_out (exactly 25,165,824 B), dead before k_av192 writes out.
  char* ws = (char*)d_ws;
  bf16*  y     = (bf16*)(ws);                              // 12,582,912 B
  unsigned char* st288 = (unsigned char*)(ws + 12582912);  // 37,748,736 B [2][288][NPB]
  unsigned char* vd8   = (unsigned char*)(ws + 50331648);  // 25,165,824 B [2][192][NPB]
  float* Gm    = (float*)(ws + 75497472);                  //     73,728 B
  float* sq    = (float*)(ws + 75571200);                  //      3,072 B
  bf16*  Mm    = (bf16*)(ws + 75574272);                   //     36,864 B
  unsigned char* qkd8 = (unsigned char*)d_out;             // 25,165,824 B (scratch)
  // FFN phase (attention buffers dead):
  bf16*  y2    = (bf16*)(ws);                              // 12,582,912 B
  unsigned char* z8  = (unsigned char*)(ws + 12582912);    // 25,165,824 B
  unsigned char* gg8 = (unsigned char*)(ws + 37748736);    // 12,582,912 B

  (void)hipMemsetAsync(Gm, 0, 73728 + 3072, stream);
  k_ln<<<dim3(512), dim3(256), 0, stream>>>(x, ln1w, ln1b, y);

  for (int hp = 0; hp < 2; ++hp) {
    // q,k,v pointwise for head pair (6 sections), fp8 out -> st288
    k_pconv_sec<<<dim3(6, 1024), dim3(256), 0, stream>>>(y, qkvw, qkvb, hp, st288, 288);
    // grouped dw-conv q+k (192 ch = 12 x 16-oc blocks) -> qkd8 (in d_out) + sumsq
    k_gconv48<<<dim3(64, 12, 2), dim3(512), 0, stream>>>(
        st288, 0, gdww, gdwb, qkd8, hp, 0, sq);
    // Gram for both heads of the pair
    k_gram_mfma<<<dim3(64, 2, 2), dim3(256), 0, stream>>>(qkd8, hp, Gm);
    // grouped dw-conv v (96 ch = 6 x 16-oc blocks) -> vd8 slots
    k_gconv48<<<dim3(64, 6, 2), dim3(512), 0, stream>>>(
        st288, 192, gdww, gdwb, vd8, hp, 1, nullptr);
  }
  k_attn_mm<<<dim3(8), dim3(256), 0, stream>>>(Gm, sq, temp, projw, Mm);
  k_av192<<<dim3(1024), dim3(256), 0, stream>>>(vd8, Mm, projb, x, out);

  k_ln<<<dim3(512), dim3(256), 0, stream>>>(out, ln2w, ln2b, y2);
  k_pconv_sec<<<dim3(4, 1024), dim3(256), 0, stream>>>(y2, pinw, pinb, -1, z8, 192);
  k_dw_gelu<<<dim3(32, 96, 2), dim3(256), 0, stream>>>(z8, dww, dwb, gg8);
  k_ek96<<<dim3(1024), dim3(256), 0, stream>>>(gg8, poutw, 96, poutb, out, out);
}

// Round 12
// 520.745 us; speedup vs baseline: 1.2846x; 1.1419x over previous
//
#include <hip/hip_runtime.h>
#include <hip/hip_bf16.h>
#include <hip/hip_fp16.h>
#include <hip/hip_fp8.h>
#include <math.h>

typedef __hip_bfloat16 bf16;
typedef __attribute__((ext_vector_type(8))) short short8;
typedef __attribute__((ext_vector_type(4))) float f32x4;

#define NPB   65536   // positions per batch (16*64*64)
#define DIMC  48
#define C2    192
#define HIDC  96
#define TT    16

static __device__ __forceinline__ float b2f(bf16 v) { return __bfloat162float(v); }
static __device__ __forceinline__ bf16  f2b(float v) { return __float2bfloat16(v); }
static __device__ __forceinline__ float bfr2f(unsigned short u) {
  union { unsigned int i; float f; } c; c.i = ((unsigned int)u) << 16; return c.f;
}
static __device__ __forceinline__ unsigned short f2us(float v) {
  return __bfloat16_as_ushort(__float2bfloat16(v));
}
static __device__ __forceinline__ unsigned char f2fp8(float v) {
  __hip_fp8_e4m3 t(v); return (unsigned char)t.__x;
}
static __device__ __forceinline__ float fp82f(unsigned char u) {
  __hip_fp8_e4m3 t; t.__x = (__hip_fp8_storage_t)u; return (float)t;
}

// ---- hardware fp8 packed converts (gfx950: OCP e4m3fn, matches __hip_fp8_e4m3) --
#if defined(__has_builtin)
#if __has_builtin(__builtin_amdgcn_cvt_pk_f32_fp8) && __has_builtin(__builtin_amdgcn_cvt_pk_fp8_f32)
#define HW_FP8 1
#endif
#endif

// decode 4 packed fp8 bytes -> 4 f32 (2 HW insts)
static __device__ __forceinline__ void fp8x4_to_f32x4(unsigned int u, float* o) {
#ifdef HW_FP8
  auto lo = __builtin_amdgcn_cvt_pk_f32_fp8(u, false);
  auto hi = __builtin_amdgcn_cvt_pk_f32_fp8(u, true);
  o[0] = lo[0]; o[1] = lo[1]; o[2] = hi[0]; o[3] = hi[1];
#else
  o[0] = fp82f(u & 0xff); o[1] = fp82f((u >> 8) & 0xff);
  o[2] = fp82f((u >> 16) & 0xff); o[3] = fp82f((u >> 24) & 0xff);
#endif
}
// encode 2 f32 -> 2 fp8 bytes in low word (1 HW inst)
static __device__ __forceinline__ unsigned int f32x2_to_fp8pair(float x, float y) {
#ifdef HW_FP8
  return (unsigned int)__builtin_amdgcn_cvt_pk_fp8_f32(x, y, 0, false) & 0xffffu;
#else
  return (unsigned int)f2fp8(x) | ((unsigned int)f2fp8(y) << 8);
#endif
}
// decode the low-word fp8 pair -> 2 f32 (1 HW inst)
static __device__ __forceinline__ void fp8pair_to_2f(unsigned int pr, float& x, float& y) {
#ifdef HW_FP8
  auto d = __builtin_amdgcn_cvt_pk_f32_fp8(pr, false);
  x = d[0]; y = d[1];
#else
  x = fp82f(pr & 0xff); y = fp82f((pr >> 8) & 0xff);
#endif
}

// pack two f32 -> half2 (u32), single v_cvt_pkrtz_f16_f32 (exact for fp8-decoded vals)
static __device__ __forceinline__ unsigned int pkh2(float x, float y) {
  auto h = __builtin_amdgcn_cvt_pkrtz(x, y);   // __fp16 ext_vector_type(2)
  return __builtin_bit_cast(unsigned int, h);
}
// dual f16 multiply, f32 accumulate: acc += a.lo*b.lo + a.hi*b.hi
static __device__ __forceinline__ float dot2f16(unsigned int a, unsigned int b, float c) {
  asm("v_dot2_f32_f16 %0, %1, %2, %0" : "+v"(c) : "v"(a), "v"(b));
  return c;
}
static __device__ __forceinline__ __half2 u2h2(unsigned int u) {
  return __builtin_bit_cast(__half2, u);
}

// ---------------- y = LN(x) over 48 channels, bf16 out (LN1 and LN2) -------------
__global__ __launch_bounds__(256) void k_ln(
    const float* __restrict__ x, const float* __restrict__ lw, const float* __restrict__ lb,
    bf16* __restrict__ y) {
  int p = blockIdx.x * 256 + threadIdx.x;   // 0..131071
  int b = p >> 16, n = p & (NPB - 1);
  const float* xb = x + ((size_t)b * DIMC) * NPB + n;
  float v[DIMC]; float s = 0.f, s2 = 0.f;
#pragma unroll
  for (int c = 0; c < DIMC; ++c) { float t = xb[(size_t)c * NPB]; v[c] = t; s += t; s2 += t * t; }
  float mu = s * (1.f / DIMC);
  float var = fmaxf(s2 * (1.f / DIMC) - mu * mu, 0.f);
  float rs = rsqrtf(var + 1e-5f);
  bf16* yb = y + ((size_t)b * DIMC) * NPB + n;
#pragma unroll
  for (int c = 0; c < DIMC; ++c) yb[(size_t)c * NPB] = f2b((v[c] - mu) * rs * lw[c] + lb[c]);
}

// ------- MFMA 1x1 conv, sectioned, fp8(x16) out. grid (NSEC, 1024) ----------------
// hp >= 0: qkv head-pair mapping (sec 0..5 -> q(2hp),q(2hp+1),k0,k1,v0,v1)
// hp <  0: plain rows sec*48 (FFN pin).
// Epilogue: fp8 bytes staged to Ot[48][132] (LDS), then full-line uchar4 stores.
__global__ __launch_bounds__(256) void k_pconv_sec(
    const bf16* __restrict__ y, const float* __restrict__ W,
    const float* __restrict__ bias, int hp, unsigned char* __restrict__ dst, int dcs) {
  __shared__ unsigned short Yl[64][130];
  __shared__ unsigned short Wl[48][72];
  __shared__ unsigned char Ot[48][132];
  int tid = threadIdx.x;
  int sec = blockIdx.x;
  int row = (hp >= 0) ? ((sec >> 1) * 192 + (2 * hp + (sec & 1)) * 48) : sec * 48;
  int bt = blockIdx.y;
  int b = bt >> 9;
  int n0 = (bt & 511) * 128;
  const unsigned short* yb = (const unsigned short*)(y + ((size_t)b * DIMC) * NPB) + n0;
  for (int j = tid; j < 48 * 32; j += 256) {       // stage Y (48 x 128)
    int c = j >> 5, sub = j & 31;
    ushort4 u = *(const ushort4*)(yb + (size_t)c * NPB + sub * 4);
    *(ushort2*)&Yl[c][sub * 4]     = make_ushort2(u.x, u.y);
    *(ushort2*)&Yl[c][sub * 4 + 2] = make_ushort2(u.z, u.w);
  }
  for (int j = tid; j < 16 * 32; j += 256) {       // zero rows 48..63
    int c = 48 + (j >> 5), sub = j & 31;
    *(ushort2*)&Yl[c][sub * 4]     = make_ushort2(0, 0);
    *(ushort2*)&Yl[c][sub * 4 + 2] = make_ushort2(0, 0);
  }
  if (tid < 48) {
    const float* wr = W + (size_t)(row + tid) * 48;
    unsigned short* wl = Wl[tid];
#pragma unroll
    for (int c = 0; c < 48; ++c) wl[c] = f2us(wr[c]);
#pragma unroll
    for (int c = 48; c < 64; ++c) wl[c] = 0;
  }
  __syncthreads();
  int wv = tid >> 6, ln = tid & 63, lq = ln >> 4, li = ln & 15;
  short8 afr[3][2];
#pragma unroll
  for (int mt = 0; mt < 3; ++mt)
#pragma unroll
    for (int ks = 0; ks < 2; ++ks)
      afr[mt][ks] = *(const short8*)&Wl[mt * 16 + li][ks * 32 + lq * 8];
#pragma unroll 1
  for (int ns = 0; ns < 2; ++ns) {
    int nn = wv * 32 + ns * 16 + li;
    short8 bfr[2];
#pragma unroll
    for (int ks = 0; ks < 2; ++ks)
#pragma unroll
      for (int j = 0; j < 8; ++j)
        bfr[ks][j] = (short)Yl[ks * 32 + lq * 8 + j][nn];
#pragma unroll
    for (int mt = 0; mt < 3; ++mt) {
      f32x4 acc = {0.f, 0.f, 0.f, 0.f};
      acc = __builtin_amdgcn_mfma_f32_16x16x32_bf16(afr[mt][0], bfr[0], acc, 0, 0, 0);
      acc = __builtin_amdgcn_mfma_f32_16x16x32_bf16(afr[mt][1], bfr[1], acc, 0, 0, 0);
      int m0 = mt * 16 + lq * 4;
      unsigned int p01 = f32x2_to_fp8pair(16.f * (acc[0] + bias[row + m0]),
                                          16.f * (acc[1] + bias[row + m0 + 1]));
      unsigned int p23 = f32x2_to_fp8pair(16.f * (acc[2] + bias[row + m0 + 2]),
                                          16.f * (acc[3] + bias[row + m0 + 3]));
      Ot[m0 + 0][nn] = (unsigned char)p01;
      Ot[m0 + 1][nn] = (unsigned char)(p01 >> 8);
      Ot[m0 + 2][nn] = (unsigned char)p23;
      Ot[m0 + 3][nn] = (unsigned char)(p23 >> 8);
    }
  }
  __syncthreads();
  for (int j = tid; j < 48 * 32; j += 256) {       // full-line stores
    int m = j >> 5, c4 = (j & 31) * 4;
    *(uchar4*)(dst + ((size_t)b * dcs + sec * 48 + m) * NPB + n0 + c4) =
        *(const uchar4*)&Ot[m][c4];
  }
}

// ------- grouped 3x3x3 conv, ci-pair half2 LDS tile, v_dot2_f32_f16 inner ---------
// grid (32, NG, 2): x = t-tile(8) x h-tile(4) [2t x 16h x 64w], y = 4-ch group.
// 512 threads (8 waves): w = tid&63, hr = tid>>6 -> 2 h-rows; 16 outputs/thread.
// PROVEN at the dot2 VALU MAC ceiling (68.3 us q+k = 100% of 69.2 us roofline).
// MFMA reformulations (R9 f16-decode, R11 raw-fp8 two-term) both lost to the
// addressing/staging VALU tax of conv-as-GEMM; dot2 form is the keeper.
__global__ __launch_bounds__(512, 8) void k_gconv48(
    const unsigned char* __restrict__ src, int sco,
    const float* __restrict__ gw, const float* __restrict__ gb,
    unsigned char* __restrict__ dst, int hp, int isV, float* __restrict__ sqout) {
  __shared__ unsigned int tile[2][4][18][66];   // 38,016 B: [ci-pair][tt][hh][w] half2
  __shared__ unsigned int Wh[2][28][4];         //    896 B: [ci-pair][tap][oc] half2
  __shared__ float red[8][4];
  int tid = threadIdx.x;
  int t0 = (blockIdx.x >> 2) * 2, h0 = (blockIdx.x & 3) * 16;
  int cbase = blockIdx.y * 4, b = blockIdx.z;
  int seg = cbase / 48, lc = cbase - seg * 48;
  int wbase = isV ? 384 + (2 * hp + seg) * 48 + lc
                  : ((seg >= 2 ? 192 : 0) + (2 * hp + (seg & 1)) * 48 + lc);
  int dch = isV ? (2 * hp + seg) * 48 + lc : cbase;
  const unsigned char* ib = src + ((size_t)b * 288 + sco + cbase) * NPB;
  for (int j = tid; j < 216; j += 512) {          // stage weights as ci-pair half2
    int o = j & 3, t2 = j >> 2;                   // t2: 0..53
    int cp = t2 / 27, tap = t2 - cp * 27;
    const float* wr = gw + (size_t)(wbase + o) * 108 + cp * 54 + tap;
    Wh[cp][tap][o] = pkh2(wr[0], wr[27]);
  }
  for (int j = tid; j < 2304; j += 512) {         // stage 2cp x 4tt x 18hh x 64w
    int sub = j & 15, r = j >> 4;                 // r: 0..143
    int cp = r / 72, rem = r - cp * 72;
    int tt = rem / 18, hh = rem - tt * 18;
    int gt = t0 + tt - 1, gh2 = h0 + hh - 1;
    unsigned int* dp = &tile[cp][tt][hh][1 + sub * 4];
    if ((unsigned)gt < 16u && (unsigned)gh2 < 64u) {
      const unsigned char* p0 = ib + (size_t)(2 * cp) * NPB + gt * 4096 + gh2 * 64 + sub * 4;
      unsigned int u0 = *(const unsigned int*)p0;
      unsigned int u1 = *(const unsigned int*)(p0 + NPB);
      float a0[4], a1[4];
      fp8x4_to_f32x4(u0, a0);
      fp8x4_to_f32x4(u1, a1);
      dp[0] = pkh2(a0[0], a1[0]);
      dp[1] = pkh2(a0[1], a1[1]);
      dp[2] = pkh2(a0[2], a1[2]);
      dp[3] = pkh2(a0[3], a1[3]);
    } else { dp[0] = 0; dp[1] = 0; dp[2] = 0; dp[3] = 0; }
  }
  for (int j = tid; j < 288; j += 512) {          // w halos
    int side = j & 1, r = j >> 1;
    int cp = r / 72, rem = r - cp * 72;
    int tt = rem / 18, hh = rem - tt * 18;
    tile[cp][tt][hh][side ? 65 : 0] = 0;
  }
  __syncthreads();
  int w = tid & 63, hr = tid >> 6;                // hr: 0..7, 2 h-rows each
  float acc[2][2][4];                             // [t][i(h)][oc]
#pragma unroll
  for (int t = 0; t < 2; ++t)
#pragma unroll
    for (int i = 0; i < 2; ++i)
#pragma unroll
      for (int o = 0; o < 4; ++o) acc[t][i][o] = 0.f;
#pragma unroll 1
  for (int cp = 0; cp < 2; ++cp) {
#pragma unroll 1
    for (int dw = 0; dw < 3; ++dw) {
      int wwl = w + dw;
      unsigned int v[4][4];
#pragma unroll
      for (int tt = 0; tt < 4; ++tt)
#pragma unroll
        for (int r = 0; r < 4; ++r) v[tt][r] = tile[cp][tt][hr * 2 + r][wwl];
#pragma unroll
      for (int dt = 0; dt < 3; ++dt)
#pragma unroll
        for (int dh = 0; dh < 3; ++dh) {
          uint4 wv = *(const uint4*)&Wh[cp][dt * 9 + dh * 3 + dw][0];
#pragma unroll
          for (int t = 0; t < 2; ++t)
#pragma unroll
            for (int i = 0; i < 2; ++i) {
              unsigned int val = v[t + dt][i + dh];
              acc[t][i][0] = dot2f16(val, wv.x, acc[t][i][0]);
              acc[t][i][1] = dot2f16(val, wv.y, acc[t][i][1]);
              acc[t][i][2] = dot2f16(val, wv.z, acc[t][i][2]);
              acc[t][i][3] = dot2f16(val, wv.w, acc[t][i][3]);
            }
        }
    }
  }
  float s[4] = {0.f, 0.f, 0.f, 0.f};
#pragma unroll
  for (int o = 0; o < 4; ++o) {
    float bias16 = 16.f * gb[wbase + o];
    size_t obase = ((size_t)b * 192 + dch + o) * NPB;
#pragma unroll
    for (int t = 0; t < 2; ++t) {
      // encode (i=0, i=1) pair in one HW cvt; rows 64B apart (full-line per wave)
      unsigned int pr = f32x2_to_fp8pair(acc[t][0][o] + bias16, acc[t][1][o] + bias16);
      size_t rb = obase + (t0 + t) * 4096 + (h0 + hr * 2) * 64 + w;
      dst[rb]      = (unsigned char)pr;
      dst[rb + 64] = (unsigned char)(pr >> 8);
      if (sqout) {
        float f0, f1; fp8pair_to_2f(pr, f0, f1);
        s[o] = fmaf(f0, f0, fmaf(f1, f1, s[o]));
      }
    }
  }
  if (sqout) {
#pragma unroll
    for (int o = 0; o < 4; ++o) {
      float sv = s[o];
#pragma unroll
      for (int off = 32; off; off >>= 1) sv += __shfl_down(sv, off);
      if ((tid & 63) == 0) red[tid >> 6][o] = sv;
    }
    __syncthreads();
    if (tid < 4) {
      int sqi = (seg < 2 ? 0 : 384) + b * 192 + (2 * hp + (seg & 1)) * 48 + lc + tid;
      float acc8 = 0.f;
#pragma unroll
      for (int k = 0; k < 8; ++k) acc8 += red[k][tid];
      atomicAdd(&sqout[sqi], acc8);
    }
  }
}

// ---------------- MFMA Gram from fp8 q,k (x16): scale cancels with norms ----------
// grid (64, 2, 2): x = 1024-wide n-chunk, y = batch, z = head-in-pair.
__global__ __launch_bounds__(256) void k_gram_mfma(
    const unsigned char* __restrict__ qkd, int hp, float* __restrict__ Gm) {
  __shared__ unsigned short qkl[2][48][264];
  int tid = threadIdx.x, b = blockIdx.y, z = blockIdx.z;
  int wv = tid >> 6, ln = tid & 63, lq = ln >> 4, li = ln & 15;
  const unsigned char* qb = qkd + ((size_t)b * 192 + z * 48) * NPB + blockIdx.x * 1024;
  const unsigned char* kb = qkd + ((size_t)b * 192 + 96 + z * 48) * NPB + blockIdx.x * 1024;
  f32x4 acc[9];
#pragma unroll
  for (int t = 0; t < 9; ++t) acc[t] = (f32x4){0.f, 0.f, 0.f, 0.f};
#pragma unroll 1
  for (int it = 0; it < 4; ++it) {
    __syncthreads();
    for (int j = tid; j < 48 * 64; j += 256) {
      int c = j >> 6, sub = j & 63;
      unsigned int uq = *(const unsigned int*)(qb + (size_t)c * NPB + it * 256 + sub * 4);
      unsigned int uk = *(const unsigned int*)(kb + (size_t)c * NPB + it * 256 + sub * 4);
      float aq[4], ak[4];
      fp8x4_to_f32x4(uq, aq);
      fp8x4_to_f32x4(uk, ak);
      *(ushort2*)&qkl[0][c][sub * 4]     = make_ushort2(f2us(aq[0]), f2us(aq[1]));
      *(ushort2*)&qkl[0][c][sub * 4 + 2] = make_ushort2(f2us(aq[2]), f2us(aq[3]));
      *(ushort2*)&qkl[1][c][sub * 4]     = make_ushort2(f2us(ak[0]), f2us(ak[1]));
      *(ushort2*)&qkl[1][c][sub * 4 + 2] = make_ushort2(f2us(ak[2]), f2us(ak[3]));
    }
    __syncthreads();
    short8 afr[3][2], bfr[3][2];
#pragma unroll
    for (int ks = 0; ks < 2; ++ks) {
      int kbase = wv * 64 + ks * 32 + lq * 8;
#pragma unroll
      for (int t = 0; t < 3; ++t) {
        afr[t][ks] = *(const short8*)&qkl[0][t * 16 + li][kbase];
        bfr[t][ks] = *(const short8*)&qkl[1][t * 16 + li][kbase];
      }
    }
#pragma unroll
    for (int mt = 0; mt < 3; ++mt)
#pragma unroll
      for (int nt = 0; nt < 3; ++nt) {
        acc[mt * 3 + nt] = __builtin_amdgcn_mfma_f32_16x16x32_bf16(afr[mt][0], bfr[nt][0], acc[mt * 3 + nt], 0, 0, 0);
        acc[mt * 3 + nt] = __builtin_amdgcn_mfma_f32_16x16x32_bf16(afr[mt][1], bfr[nt][1], acc[mt * 3 + nt], 0, 0, 0);
      }
  }
  __syncthreads();
  float* red = (float*)&qkl[0][0][0];
  if (wv > 0) {
    float* rw = red + (size_t)(wv - 1) * 2304;
#pragma unroll
    for (int t = 0; t < 9; ++t)
#pragma unroll
      for (int r = 0; r < 4; ++r)
        rw[t * 256 + r * 64 + ln] = acc[t][r];
  }
  __syncthreads();
  if (wv == 0) {
    int hd = 2 * hp + z;
    float* gbase = Gm + (size_t)(b * 4 + hd) * 2304;
#pragma unroll
    for (int t = 0; t < 9; ++t) {
      int mt = t / 3, nt = t - mt * 3;
#pragma unroll
      for (int r = 0; r < 4; ++r) {
        int o = t * 256 + r * 64 + ln;
        float v = acc[t][r] + red[o] + red[2304 + o] + red[4608 + o];
        atomicAdd(&gbase[(mt * 16 + lq * 4 + r) * 48 + nt * 16 + li], v);
      }
    }
  }
}

// ------- tiny: per-(b,head) softmax(norm G) + proj fold -> Mm[b][48][192] bf16 ----
__global__ __launch_bounds__(256) void k_attn_mm(
    const float* __restrict__ Gm, const float* __restrict__ sq, const float* __restrict__ temp,
    const float* __restrict__ pw, bf16* __restrict__ Mm) {
  __shared__ float A[48][48];
  __shared__ float nk[48];
  int tid = threadIdx.x;
  int bh = blockIdx.x; int b = bh >> 2, hd = bh & 3;
  if (tid >= 64 && tid < 112)
    nk[tid - 64] = fmaxf(sqrtf(sq[384 + bh * 48 + tid - 64]), 1e-12f);
  __syncthreads();
  if (tid < 48) {
    float tv = temp[hd];
    float rq = 1.f / fmaxf(sqrtf(sq[bh * 48 + tid]), 1e-12f);
    const float* grow = Gm + (size_t)bh * 2304 + tid * 48;
    float mx = -1e30f;
#pragma unroll
    for (int d = 0; d < 48; ++d) mx = fmaxf(mx, grow[d] * rq / nk[d] * tv);
    float sum = 0.f;
#pragma unroll
    for (int d = 0; d < 48; ++d) {
      float e = expf(grow[d] * rq / nk[d] * tv - mx);
      A[tid][d] = e; sum += e;
    }
    float inv = 1.f / sum;
#pragma unroll
    for (int d = 0; d < 48; ++d) A[tid][d] *= inv;
  }
  __syncthreads();
  for (int j = tid; j < 2304; j += 256) {
    int m = j / 48, d = j - m * 48;
    float a = 0.f;
#pragma unroll
    for (int c = 0; c < 48; ++c) a = fmaf(pw[m * 192 + hd * 48 + c], A[c][d], a);
    Mm[((size_t)b * 48 + m) * 192 + hd * 48 + d] = f2b(a * 0.0625f);
  }
}

// ------- K=192 GEMM: out = x + pb + Mm[b] @ v8[b]  (fp8 v, bf16 MFMA) -------------
__global__ __launch_bounds__(256) void k_av192(
    const unsigned char* __restrict__ vd8, const bf16* __restrict__ Mm,
    const float* __restrict__ pb, const float* __restrict__ x, float* __restrict__ outp) {
  __shared__ unsigned short Yl[96][130];
  __shared__ unsigned short Ml[48][200];
  int tid = threadIdx.x;
  int bt = blockIdx.x;
  int b = bt >> 9;
  int n0 = (bt & 511) * 128;
  int wv = tid >> 6, ln = tid & 63, lq = ln >> 4, li = ln & 15;
  const unsigned short* mb = (const unsigned short*)(Mm + (size_t)b * 48 * 192);
  for (int j = tid; j < 48 * 48; j += 256) {       // stage M (48 x 192)
    int m = j / 48, c4 = j - m * 48;
    *(ushort4*)&Ml[m][c4 * 4] = *(const ushort4*)(mb + m * 192 + c4 * 4);
  }
  const unsigned char* vb = vd8 + ((size_t)b * C2) * NPB + n0;
  f32x4 acc[3][2];
#pragma unroll
  for (int mt = 0; mt < 3; ++mt)
#pragma unroll
    for (int ns = 0; ns < 2; ++ns) acc[mt][ns] = (f32x4){0.f, 0.f, 0.f, 0.f};
#pragma unroll 1
  for (int s = 0; s < 2; ++s) {
    __syncthreads();
    for (int j = tid; j < 96 * 32; j += 256) {     // stage V half (96 x 128), decode
      int c = j >> 5, sub = j & 31;
      unsigned int u = *(const unsigned int*)(vb + (size_t)(s * 96 + c) * NPB + sub * 4);
      float a[4]; fp8x4_to_f32x4(u, a);
      *(ushort2*)&Yl[c][sub * 4]     = make_ushort2(f2us(a[0]), f2us(a[1]));
      *(ushort2*)&Yl[c][sub * 4 + 2] = make_ushort2(f2us(a[2]), f2us(a[3]));
    }
    __syncthreads();
#pragma unroll 1
    for (int ns = 0; ns < 2; ++ns) {
      int nn = wv * 32 + ns * 16 + li;
      short8 bfr[3];
#pragma unroll
      for (int ks = 0; ks < 3; ++ks)
#pragma unroll
        for (int j = 0; j < 8; ++j)
          bfr[ks][j] = (short)Yl[ks * 32 + lq * 8 + j][nn];
#pragma unroll
      for (int mt = 0; mt < 3; ++mt) {
        short8 a0 = *(const short8*)&Ml[mt * 16 + li][s * 96 + lq * 8];
        short8 a1 = *(const short8*)&Ml[mt * 16 + li][s * 96 + 32 + lq * 8];
        short8 a2 = *(const short8*)&Ml[mt * 16 + li][s * 96 + 64 + lq * 8];
        acc[mt][ns] = __builtin_amdgcn_mfma_f32_16x16x32_bf16(a0, bfr[0], acc[mt][ns], 0, 0, 0);
        acc[mt][ns] = __builtin_amdgcn_mfma_f32_16x16x32_bf16(a1, bfr[1], acc[mt][ns], 0, 0, 0);
        acc[mt][ns] = __builtin_amdgcn_mfma_f32_16x16x32_bf16(a2, bfr[2], acc[mt][ns], 0, 0, 0);
      }
    }
  }
#pragma unroll
  for (int ns = 0; ns < 2; ++ns) {
    int nn = wv * 32 + ns * 16 + li;
#pragma unroll
    for (int mt = 0; mt < 3; ++mt)
#pragma unroll
      for (int r = 0; r < 4; ++r) {
        int m = mt * 16 + lq * 4 + r;
        size_t idx = ((size_t)b * DIMC + m) * NPB + n0 + nn;
        outp[idx] = x[idx] + pb[m] + acc[mt][ns][r];
      }
  }
}

// ---------------- MFMA K=96 GEMM (pout), fp8(x16) input: out = addend+bias+W@g ----
__global__ __launch_bounds__(256) void k_ek96(
    const unsigned char* __restrict__ V, const float* __restrict__ W, int wrs,
    const float* __restrict__ bias, const float* __restrict__ addend, float* __restrict__ outp) {
  __shared__ unsigned short Yl[96][130];
  __shared__ unsigned short Wl[48][104];
  int tid = threadIdx.x;
  int bt = blockIdx.x;
  int b = bt >> 9;
  int n0 = (bt & 511) * 128;
  const unsigned char* vb = V + ((size_t)b * 96) * NPB + n0;
  for (int j = tid; j < 96 * 32; j += 256) {
    int c = j >> 5, sub = j & 31;
    unsigned int u = *(const unsigned int*)(vb + (size_t)c * NPB + sub * 4);
    float a[4]; fp8x4_to_f32x4(u, a);
    *(ushort2*)&Yl[c][sub * 4]     = make_ushort2(f2us(a[0]), f2us(a[1]));
    *(ushort2*)&Yl[c][sub * 4 + 2] = make_ushort2(f2us(a[2]), f2us(a[3]));
  }
  if (tid < 48) {
    const float* wr = W + (size_t)tid * wrs;
    unsigned short* wl = Wl[tid];
#pragma unroll
    for (int c = 0; c < 96; ++c) wl[c] = f2us(wr[c] * 0.0625f);   // cancel x16
  }
  __syncthreads();
  int wv = tid >> 6, ln = tid & 63, lq = ln >> 4, li = ln & 15;
  short8 afr[3][3];
#pragma unroll
  for (int mt = 0; mt < 3; ++mt)
#pragma unroll
    for (int ks = 0; ks < 3; ++ks)
      afr[mt][ks] = *(const short8*)&Wl[mt * 16 + li][ks * 32 + lq * 8];
#pragma unroll 1
  for (int ns = 0; ns < 2; ++ns) {
    int nn = wv * 32 + ns * 16 + li;
    short8 bfr[3];
#pragma unroll
    for (int ks = 0; ks < 3; ++ks)
#pragma unroll
      for (int j = 0; j < 8; ++j)
        bfr[ks][j] = (short)Yl[ks * 32 + lq * 8 + j][nn];
#pragma unroll
    for (int mt = 0; mt < 3; ++mt) {
      f32x4 acc = {0.f, 0.f, 0.f, 0.f};
      acc = __builtin_amdgcn_mfma_f32_16x16x32_bf16(afr[mt][0], bfr[0], acc, 0, 0, 0);
      acc = __builtin_amdgcn_mfma_f32_16x16x32_bf16(afr[mt][1], bfr[1], acc, 0, 0, 0);
      acc = __builtin_amdgcn_mfma_f32_16x16x32_bf16(afr[mt][2], bfr[2], acc, 0, 0, 0);
#pragma unroll
      for (int r = 0; r < 4; ++r) {
        int m = mt * 16 + lq * 4 + r;
        size_t idx = ((size_t)b * DIMC + m) * NPB + n0 + nn;
        outp[idx] = acc[r] + addend[idx] + bias[m];
      }
    }
  }
}

// ------- depthwise 3x3x3 + GELU gate; ch-pair half2 tile, ONE staging pass --------
// grid (32, 96, 2): x = t-tile(8) x h-tile(4) [2t x 16h x 64w], y = ch pair (c,c+96).
__global__ __launch_bounds__(256) void k_dw_gelu(
    const unsigned char* __restrict__ z, const float* __restrict__ dwW,
    const float* __restrict__ dwB, unsigned char* __restrict__ g) {
  __shared__ unsigned int tile[4][18][68];   // 19,584 B; row stride 272B
  int tid = threadIdx.x;
  int t0 = (blockIdx.x >> 2) * 2, h0 = (blockIdx.x & 3) * 16;
  int c = blockIdx.y, b = blockIdx.z;
  int wq = tid & 15, hq = tid >> 4;      // wq: w-quad, hq: h-row 0..15
  int w0 = wq * 4;
  const unsigned char* zp0 = z + ((size_t)b * C2 + c) * NPB;
  const unsigned char* zp1 = zp0 + (size_t)HIDC * NPB;
  for (int j = tid; j < 72 * 16; j += 256) {     // stage 4tt x 18hh x 64w, both ch
    int r = j >> 4, sub = j & 15;
    int tt = r / 18, hh = r - tt * 18;
    int gt = t0 + tt - 1, gh = h0 + hh - 1;
    unsigned int* dp = &tile[tt][hh][1 + sub * 4];
    if ((unsigned)gt < 16u && (unsigned)gh < 64u) {
      size_t off = (size_t)gt * 4096 + gh * 64 + sub * 4;
      unsigned int u0 = *(const unsigned int*)(zp0 + off);
      unsigned int u1 = *(const unsigned int*)(zp1 + off);
      float a0[4], a1[4];
      fp8x4_to_f32x4(u0, a0);
      fp8x4_to_f32x4(u1, a1);
      dp[0] = pkh2(a0[0], a1[0]);
      dp[1] = pkh2(a0[1], a1[1]);
      dp[2] = pkh2(a0[2], a1[2]);
      dp[3] = pkh2(a0[3], a1[3]);
    } else { dp[0] = 0; dp[1] = 0; dp[2] = 0; dp[3] = 0; }
  }
  for (int j = tid; j < 144; j += 256) {         // w halos
    int r = j >> 1, side = j & 1;
    int tt = r / 18, hh = r - tt * 18;
    tile[tt][hh][side ? 65 : 0] = 0;
  }
  // pack weight pairs {w_c[tap], w_c96[tap]} (uniform per block)
  unsigned int wpk[27];
  {
    const float* wt0 = dwW + (size_t)c * 27;
    const float* wt1 = dwW + (size_t)(c + HIDC) * 27;
#pragma unroll
    for (int tap = 0; tap < 27; ++tap) wpk[tap] = pkh2(wt0[tap], wt1[tap]);
  }
  __syncthreads();
  __half2 hacc[2][4];                            // [t][k] {sum_c, sum_c96}
#pragma unroll
  for (int t = 0; t < 2; ++t)
#pragma unroll
    for (int k = 0; k < 4; ++k) hacc[t][k] = u2h2(0u);
#pragma unroll 1
  for (int dh = 0; dh < 3; ++dh) {
    unsigned int v[4][6];                        // rows hq+dh, cols w0..w0+5
#pragma unroll
    for (int tt = 0; tt < 4; ++tt) {
      uint4 q4 = *(const uint4*)&tile[tt][hq + dh][w0];
      uint2 q2 = *(const uint2*)&tile[tt][hq + dh][w0 + 4];
      v[tt][0] = q4.x; v[tt][1] = q4.y; v[tt][2] = q4.z; v[tt][3] = q4.w;
      v[tt][4] = q2.x; v[tt][5] = q2.y;
    }
#pragma unroll
    for (int dt = 0; dt < 3; ++dt)
#pragma unroll
      for (int dw = 0; dw < 3; ++dw) {
        __half2 wk = u2h2(wpk[dt * 9 + dh * 3 + dw]);
#pragma unroll
        for (int t = 0; t < 2; ++t)
#pragma unroll
          for (int k = 0; k < 4; ++k)
            hacc[t][k] = __hfma2(u2h2(v[t + dt][dw + k]), wk, hacc[t][k]);
      }
  }
  float b1 = dwB[c], b2v = dwB[c + HIDC];
  size_t obase = ((size_t)b * HIDC + c) * NPB;
#pragma unroll
  for (int t = 0; t < 2; ++t) {
    float e[4];
#pragma unroll
    for (int k = 0; k < 4; ++k) {
      float x1v = __low2float(hacc[t][k]) * 0.0625f + b1;
      float x2v = __high2float(hacc[t][k]) * 0.0625f + b2v;
      float ge = 0.5f * x1v * (1.f + erff(x1v * 0.70710678118654752f));
      e[k] = 16.f * ge * x2v;
    }
    unsigned int p01 = f32x2_to_fp8pair(e[0], e[1]);
    unsigned int p23 = f32x2_to_fp8pair(e[2], e[3]);
    unsigned int packed = p01 | (p23 << 16);
    *(unsigned int*)(g + obase + (t0 + t) * 4096 + (h0 + hq) * 64 + w0) = packed;
  }
}

extern "C" void kernel_launch(void* const* d_in, const int* in_sizes, int n_in,
                              void* d_out, int out_size, void* d_ws, size_t ws_size,
                              hipStream_t stream) {
  (void)in_sizes; (void)n_in; (void)out_size; (void)ws_size;
  const float* x     = (const float*)d_in[0];
  const float* ln1w  = (const float*)d_in[1];
  const float* ln1b  = (const float*)d_in[2];
  const float* qkvw  = (const float*)d_in[3];
  const float* qkvb  = (const float*)d_in[4];
  const float* gdww  = (const float*)d_in[5];
  const float* gdwb  = (const float*)d_in[6];
  const float* temp  = (const float*)d_in[7];
  const float* projw = (const float*)d_in[8];
  const float* projb = (const float*)d_in[9];
  const float* ln2w  = (const float*)d_in[10];
  const float* ln2b  = (const float*)d_in[11];
  const float* pinw  = (const float*)d_in[12];
  const float* pinb  = (const float*)d_in[13];
  const float* dww   = (const float*)d_in[14];
  const float* dwb   = (const float*)d_in[15];
  const float* poutw = (const float*)d_in[16];
  const float* poutb = (const float*)d_in[17];
  float* out = (float*)d_out;

  // Workspace: y 12.6M | st288 37.7M | vd8 25.2M | Gm/sq/Mm tail -> 75.61M (proven)
  // qkd8 lives in d_out (exactly 25,165,824 B), dead before k_av192 writes out.
  char* ws = (char*)d_ws;
  bf16*  y     = (bf16*)(ws);                              // 12,582,912 B
  unsigned char* st288 = (unsigned char*)(ws + 12582912);  // 37,748,736 B [2][288][NPB]
  unsigned char* vd8   = (unsigned char*)(ws + 50331648);  // 25,165,824 B [2][192][NPB]
  float* Gm    = (float*)(ws + 75497472);                  //     73,728 B
  float* sq    = (float*)(ws + 75571200);                  //      3,072 B
  bf16*  Mm    = (bf16*)(ws + 75574272);                   //     36,864 B
  unsigned char* qkd8 = (unsigned char*)d_out;             // 25,165,824 B (scratch)
  // FFN phase (attention buffers dead):
  bf16*  y2    = (bf16*)(ws);                              // 12,582,912 B
  unsigned char* z8  = (unsigned char*)(ws + 12582912);    // 25,165,824 B
  unsigned char* gg8 = (unsigned char*)(ws + 37748736);    // 12,582,912 B

  (void)hipMemsetAsync(Gm, 0, 73728 + 3072, stream);
  k_ln<<<dim3(512), dim3(256), 0, stream>>>(x, ln1w, ln1b, y);

  for (int hp = 0; hp < 2; ++hp) {
    // q,k,v pointwise for head pair (6 sections), fp8 out -> st288
    k_pconv_sec<<<dim3(6, 1024), dim3(256), 0, stream>>>(y, qkvw, qkvb, hp, st288, 288);
    // grouped dw-conv q+k (192 ch, 48 groups) -> qkd8 (in d_out) + sumsq
    k_gconv48<<<dim3(32, 48, 2), dim3(512), 0, stream>>>(
        st288, 0, gdww, gdwb, qkd8, hp, 0, sq);
    // Gram for both heads of the pair
    k_gram_mfma<<<dim3(64, 2, 2), dim3(256), 0, stream>>>(qkd8, hp, Gm);
    // grouped dw-conv v (96 ch, 24 groups) -> vd8 slots
    k_gconv48<<<dim3(32, 24, 2), dim3(512), 0, stream>>>(
        st288, 192, gdww, gdwb, vd8, hp, 1, nullptr);
  }
  k_attn_mm<<<dim3(8), dim3(256), 0, stream>>>(Gm, sq, temp, projw, Mm);
  k_av192<<<dim3(1024), dim3(256), 0, stream>>>(vd8, Mm, projb, x, out);

  k_ln<<<dim3(512), dim3(256), 0, stream>>>(out, ln2w, ln2b, y2);
  k_pconv_sec<<<dim3(4, 1024), dim3(256), 0, stream>>>(y2, pinw, pinb, -1, z8, 192);
  k_dw_gelu<<<dim3(32, 96, 2), dim3(256), 0, stream>>>(z8, dww, dwb, gg8);
  k_ek96<<<dim3(1024), dim3(256), 0, stream>>>(gg8, poutw, 96, poutb, out, out);
}